// Round 7
// baseline (509.229 us; speedup 1.0000x reference)
//
#include <hip/hip_runtime.h>
#include <hip/hip_bf16.h>
#include <math.h>

#define B_   4
#define S_   4096
#define D_   1024
#define H_   16
#define DH_  64
#define BS_  (B_ * S_)     // 16384 rows
#define N3_  3072          // 3 * INNER

using bf16 = __hip_bfloat16;
typedef __attribute__((ext_vector_type(8))) short bf16x8;
typedef __attribute__((ext_vector_type(4))) float f32x4;

#define GAS __attribute__((address_space(1)))
#define LAS __attribute__((address_space(3)))

__device__ __forceinline__ void gload_lds16(const bf16* g, bf16* l) {
  __builtin_amdgcn_global_load_lds((const GAS void*)g, (LAS void*)l, 16, 0, 0);
}

__device__ __forceinline__ float bf2f(short u) {
  unsigned int x = ((unsigned int)(unsigned short)u) << 16;
  return __builtin_bit_cast(float, x);
}

// ------------- fused weight cast+transpose: all 4 weights, one launch ------
__global__ __launch_bounds__(256)
void transpose_cast4(const float* __restrict__ Wqkv, const float* __restrict__ Wo,
                     const float* __restrict__ W1, const float* __restrict__ W2,
                     bf16* __restrict__ wqkvt, bf16* __restrict__ wot,
                     bf16* __restrict__ w1t, bf16* __restrict__ w2t)
{
  __shared__ float tile[32][33];
  int gx = blockIdx.x;
  const float* W; bf16* Wt; int N, xo;
  if (gx < 96)        { W = Wqkv; Wt = wqkvt; N = N3_; xo = gx; }
  else if (gx < 128)  { W = Wo;   Wt = wot;   N = D_;  xo = gx - 96; }
  else if (gx < 160)  { W = W1;   Wt = w1t;   N = D_;  xo = gx - 128; }
  else                { W = W2;   Wt = w2t;   N = D_;  xo = gx - 160; }
  int n0 = xo * 32, k0 = blockIdx.y * 32;
  int tx = threadIdx.x & 31, ty = threadIdx.x >> 5;   // 32 x 8
#pragma unroll
  for (int j = 0; j < 32; j += 8)
    tile[ty + j][tx] = W[(size_t)(k0 + ty + j) * N + n0 + tx];
  __syncthreads();
#pragma unroll
  for (int j = 0; j < 32; j += 8)
    Wt[(size_t)(n0 + ty + j) * 1024 + k0 + tx] = __float2bfloat16(tile[tx][ty + j]);
}

// ---------------- LayerNorm (+ optional PE), fp32 or bf16 input -> bf16 ----
template<bool PE, bool INBF16>
__global__ __launch_bounds__(256)
void ln_kernel(const float* __restrict__ Xf, const bf16* __restrict__ Xb,
               const float* __restrict__ G, const float* __restrict__ Bv,
               bf16* __restrict__ out)
{
  int row = blockIdx.x;                // b*S + s
  int t = threadIdx.x;
  float4 v;
  if (INBF16) {
    ushort4 u = ((const ushort4*)Xb)[(size_t)row * (D_ / 4) + t];
    v.x = bf2f(u.x); v.y = bf2f(u.y); v.z = bf2f(u.z); v.w = bf2f(u.w);
  } else {
    v = ((const float4*)(Xf + (size_t)row * D_))[t];
  }
  float s  = v.x + v.y + v.z + v.w;
  float ss = v.x * v.x + v.y * v.y + v.z * v.z + v.w * v.w;
#pragma unroll
  for (int o = 32; o > 0; o >>= 1) { s += __shfl_xor(s, o); ss += __shfl_xor(ss, o); }
  __shared__ float red[8];
  int wid = t >> 6, lane = t & 63;
  if (lane == 0) { red[wid] = s; red[4 + wid] = ss; }
  __syncthreads();
  s  = red[0] + red[1] + red[2] + red[3];
  ss = red[4] + red[5] + red[6] + red[7];
  float mean = s * (1.0f / D_);
  float var  = ss * (1.0f / D_) - mean * mean;
  float rs   = rsqrtf(var + 1e-6f);
  int d0 = t * 4;
  const float4 g4 = ((const float4*)G)[t];
  const float4 b4 = ((const float4*)Bv)[t];
  float o0 = (v.x - mean) * rs * g4.x + b4.x;
  float o1 = (v.y - mean) * rs * g4.y + b4.y;
  float o2 = (v.z - mean) * rs * g4.z + b4.z;
  float o3 = (v.w - mean) * rs * g4.w + b4.w;
  if (PE) {
    const float C = -0.0089944730194f;   // -ln(10000)/1024
    float p = (float)(row & (S_ - 1));
    float sn, cs;
    __sincosf(p * __expf((float)d0 * C), &sn, &cs);        o0 += sn; o1 += cs;
    __sincosf(p * __expf((float)(d0 + 2) * C), &sn, &cs);  o2 += sn; o3 += cs;
  }
  ushort4 pk; bf16 tmp;
  tmp = __float2bfloat16(o0); pk.x = *(unsigned short*)&tmp;
  tmp = __float2bfloat16(o1); pk.y = *(unsigned short*)&tmp;
  tmp = __float2bfloat16(o2); pk.z = *(unsigned short*)&tmp;
  tmp = __float2bfloat16(o3); pk.w = *(unsigned short*)&tmp;
  ((ushort4*)out)[(size_t)row * (D_ / 4) + t] = pk;
}

// ---------------- 256x256 8-phase bf16 MFMA GEMM ---------------------------
// Structure unchanged from r6 (T2 LDS swizzle: conflicts=0; T1 2D-chunk XCD
// swizzle: FETCH 215->78MB). Epilogues reworked: x2 residual stream is bf16.
enum { EPI_BF16 = 0, EPI_BIAS_RES_BF16 = 1, EPI_BIAS_GELU_BF16 = 2, EPI_BIAS_RESB_F32 = 3 };

#define MFMA_ __builtin_amdgcn_mfma_f32_16x16x32_bf16

template<int EPI>
__global__ __launch_bounds__(512)
void gemm256(const bf16* __restrict__ A, const bf16* __restrict__ Bt,
             float* __restrict__ Cf, bf16* __restrict__ Cb,
             const float* __restrict__ bias, const float* __restrict__ resf,
             const bf16* __restrict__ resb, int M, int N, int K)
{
  extern __shared__ __align__(16) char smem[];
  bf16* lds = (bf16*)smem;

  const int t = threadIdx.x;
  const int wid = t >> 6, lane = t & 63;
  const int wr = wid >> 2, wc = wid & 3;        // 2 x 4 waves
  // XCD-aware 2D-chunked swizzle (nty==64, ntx%4==0, grid%8==0)
  const int bid = blockIdx.x;
  const int c = bid & 7;
  const int w = bid >> 3;
  const int sst = w >> 4;
  const int ii = w & 15;
  const int txg = sst >> 1, tyg = sst & 1;
  const int iy = ii & 3, ix = ii >> 2;
  const int ty = c * 8 + tyg * 4 + iy;
  const int tx = txg * 4 + ix;
  const int m0 = ty << 8, n0 = tx << 8;

  const bf16* Ab = A + (size_t)m0 * K;
  const bf16* Bb = Bt + (size_t)n0 * K;

  const int srow = t >> 2;
  const int scol = (((t & 3) ^ ((t >> 3) & 3)) * 8);
  const int NT = K >> 6;
  const int fr = lane & 15;
  const int fksw = (((lane >> 4) ^ ((lane >> 1) & 3)) * 8);

  f32x4 acc[8][4] = {};

  #define LDSHALF(b, mat, kh) (lds + (((((b) << 1) + (mat)) << 1) + (kh)) * 8192)

  #define STAGE(kt, mat, kh) do {                                              \
    bf16* _dst = LDSHALF((kt) & 1, (mat), (kh)) + t * 8;                       \
    const bf16* _sb = ((mat) == 0 ? Ab : Bb) + (size_t)srow * K                \
                      + ((((kt) & (NT - 1))) << 6) + (kh) * 32 + scol;         \
    gload_lds16(_sb, _dst);                                                    \
    gload_lds16(_sb + (size_t)128 * K, _dst + 4096);                           \
  } while (0)

  STAGE(0, 0, 0); STAGE(0, 1, 0);
  STAGE(0, 0, 1); STAGE(0, 1, 1);
  asm volatile("s_waitcnt vmcnt(4)" ::: "memory");
  __builtin_amdgcn_s_barrier();

#pragma unroll 2
  for (int kt = 0; kt < NT; ++kt) {
    const int cur = kt & 1;
    const bf16* hA0 = LDSHALF(cur, 0, 0);
    const bf16* hB0 = LDSHALF(cur, 1, 0);
    const bf16* hA1 = LDSHALF(cur, 0, 1);
    const bf16* hB1 = LDSHALF(cur, 1, 1);
    bf16x8 a[8], b0, b1, b2, b3;

    // ---- phase 1: ks=0, ni=0,1 ----
#pragma unroll
    for (int mi = 0; mi < 8; ++mi)
      a[mi] = *(const bf16x8*)&hA0[(wr * 128 + mi * 16 + fr) * 32 + fksw];
    b0 = *(const bf16x8*)&hB0[(wc * 64 +  0 + fr) * 32 + fksw];
    b1 = *(const bf16x8*)&hB0[(wc * 64 + 16 + fr) * 32 + fksw];
    STAGE(kt + 1, 0, 0);
    __builtin_amdgcn_s_barrier();
    __builtin_amdgcn_s_setprio(1);
#pragma unroll
    for (int mi = 0; mi < 8; ++mi) {
      acc[mi][0] = MFMA_(a[mi], b0, acc[mi][0], 0, 0, 0);
      acc[mi][1] = MFMA_(a[mi], b1, acc[mi][1], 0, 0, 0);
    }
    __builtin_amdgcn_s_setprio(0);
    __builtin_amdgcn_s_barrier();

    // ---- phase 2: ks=0, ni=2,3 ----
    b2 = *(const bf16x8*)&hB0[(wc * 64 + 32 + fr) * 32 + fksw];
    b3 = *(const bf16x8*)&hB0[(wc * 64 + 48 + fr) * 32 + fksw];
    STAGE(kt + 1, 1, 0);
    __builtin_amdgcn_s_barrier();
    __builtin_amdgcn_s_setprio(1);
#pragma unroll
    for (int mi = 0; mi < 8; ++mi) {
      acc[mi][2] = MFMA_(a[mi], b2, acc[mi][2], 0, 0, 0);
      acc[mi][3] = MFMA_(a[mi], b3, acc[mi][3], 0, 0, 0);
    }
    __builtin_amdgcn_s_setprio(0);
    asm volatile("s_waitcnt vmcnt(4)" ::: "memory");
    __builtin_amdgcn_s_barrier();

    // ---- phase 3: ks=1, ni=0,1 ----
#pragma unroll
    for (int mi = 0; mi < 8; ++mi)
      a[mi] = *(const bf16x8*)&hA1[(wr * 128 + mi * 16 + fr) * 32 + fksw];
    b0 = *(const bf16x8*)&hB1[(wc * 64 +  0 + fr) * 32 + fksw];
    b1 = *(const bf16x8*)&hB1[(wc * 64 + 16 + fr) * 32 + fksw];
    STAGE(kt + 1, 0, 1);
    __builtin_amdgcn_s_barrier();
    __builtin_amdgcn_s_setprio(1);
#pragma unroll
    for (int mi = 0; mi < 8; ++mi) {
      acc[mi][0] = MFMA_(a[mi], b0, acc[mi][0], 0, 0, 0);
      acc[mi][1] = MFMA_(a[mi], b1, acc[mi][1], 0, 0, 0);
    }
    __builtin_amdgcn_s_setprio(0);
    __builtin_amdgcn_s_barrier();

    // ---- phase 4: ks=1, ni=2,3 ----
    b2 = *(const bf16x8*)&hB1[(wc * 64 + 32 + fr) * 32 + fksw];
    b3 = *(const bf16x8*)&hB1[(wc * 64 + 48 + fr) * 32 + fksw];
    STAGE(kt + 1, 1, 1);
    __builtin_amdgcn_s_barrier();
    __builtin_amdgcn_s_setprio(1);
#pragma unroll
    for (int mi = 0; mi < 8; ++mi) {
      acc[mi][2] = MFMA_(a[mi], b2, acc[mi][2], 0, 0, 0);
      acc[mi][3] = MFMA_(a[mi], b3, acc[mi][3], 0, 0, 0);
    }
    __builtin_amdgcn_s_setprio(0);
    asm volatile("s_waitcnt vmcnt(4)" ::: "memory");
    __builtin_amdgcn_s_barrier();
  }
  asm volatile("s_waitcnt vmcnt(0)" ::: "memory");

  // ---- epilogue ----
#pragma unroll
  for (int mi = 0; mi < 8; ++mi) {
    int rowb = m0 + wr * 128 + mi * 16 + (lane >> 4) * 4;
#pragma unroll
    for (int ni = 0; ni < 4; ++ni) {
      int col = n0 + wc * 64 + ni * 16 + fr;
#pragma unroll
      for (int j = 0; j < 4; ++j) {
        int row = rowb + j;
        float v = acc[mi][ni][j];
        if (EPI == EPI_BF16) {
          Cb[(size_t)row * N + col] = __float2bfloat16(v);
        } else if (EPI == EPI_BIAS_RES_BF16) {
          Cb[(size_t)row * N + col] =
            __float2bfloat16(v + bias[col] + resf[(size_t)row * N + col]);
        } else if (EPI == EPI_BIAS_GELU_BF16) {
          float u = v + bias[col];
          u = 0.5f * u * (1.0f + erff(u * 0.70710678118654752f));
          Cb[(size_t)row * N + col] = __float2bfloat16(u);
        } else {
          Cf[(size_t)row * N + col] =
            v + bias[col] + bf2f(*(const short*)&resb[(size_t)row * N + col]);
        }
      }
    }
  }
  #undef STAGE
  #undef LDSHALF
}

// ---------------- ctx: num = exp(k)^T @ v, den = sum exp(k), per chunk -----
// No max-subtraction: |k| <~ 6 so exp(k) <= ~400 — fp32-safe.
// LDS as padded f32x4[32][17] (pad breaks 16-way write conflicts); inner loop
// 1 scalar + 4 b128 broadcast reads per sl (was 17 scalar reads).
__global__ __launch_bounds__(256)
void ctx_partial(const bf16* __restrict__ qkv, float* __restrict__ pctx,
                 float* __restrict__ pden)
{
  int blk = blockIdx.x;                  // bh*16 + chunk
  int chunk = blk & 15, bh = blk >> 4;
  int b = bh >> 4, h = bh & 15;
  int t = threadIdx.x, d = t & 63, eg = t >> 6;
  int sl0 = t >> 3, dd0 = (t & 7) * 8;
  __shared__ f32x4 kc4[32][17];
  __shared__ f32x4 vc4[32][17];
  f32x4 acc0 = {}, acc1 = {}, acc2 = {}, acc3 = {};
  float dacc = 0.0f;
  const unsigned short* q16 = (const unsigned short*)qkv;
  const float* kcf = (const float*)&kc4[0][0];    // row stride 68 floats
  for (int c0 = 0; c0 < 256; c0 += 32) {
    int s = chunk * 256 + c0 + sl0;
    size_t base = (size_t)(b * S_ + s) * N3_;
    bf16x8 k8 = *(const bf16x8*)(q16 + base + D_ + h * DH_ + dd0);
    bf16x8 v8 = *(const bf16x8*)(q16 + base + 2 * D_ + h * DH_ + dd0);
    f32x4 kv0, kv1, vv0, vv1;
#pragma unroll
    for (int j = 0; j < 4; j++) {
      kv0[j] = __expf(bf2f(k8[j]));
      kv1[j] = __expf(bf2f(k8[4 + j]));
      vv0[j] = bf2f(v8[j]);
      vv1[j] = bf2f(v8[4 + j]);
    }
    kc4[sl0][(dd0 >> 2) + 0] = kv0;
    kc4[sl0][(dd0 >> 2) + 1] = kv1;
    vc4[sl0][(dd0 >> 2) + 0] = vv0;
    vc4[sl0][(dd0 >> 2) + 1] = vv1;
    __syncthreads();
#pragma unroll 8
    for (int sl = 0; sl < 32; ++sl) {
      float p = kcf[sl * 68 + d];
      dacc += p;
      acc0 += p * vc4[sl][eg * 4 + 0];
      acc1 += p * vc4[sl][eg * 4 + 1];
      acc2 += p * vc4[sl][eg * 4 + 2];
      acc3 += p * vc4[sl][eg * 4 + 3];
    }
    __syncthreads();
  }
  float* po = &pctx[((size_t)blk * 64 + d) * 64 + eg * 16];
  *(f32x4*)(po +  0) = acc0;
  *(f32x4*)(po +  4) = acc1;
  *(f32x4*)(po +  8) = acc2;
  *(f32x4*)(po + 12) = acc3;
  if (eg == 0) pden[blk * 64 + d] = dacc;
}

// ---------------- merge partials + normalize: grid = bh*4 quarters ---------
__global__ __launch_bounds__(256)
void ctx_merge(const float* __restrict__ pctx, const float* __restrict__ pden,
               float* __restrict__ ctx)
{
  int blk = blockIdx.x;            // bh*4 + quarter
  int bh = blk >> 2, qtr = blk & 3;
  int t = threadIdx.x;
  __shared__ float rden[16];
  if (t < 16) {
    float s = 0.0f;
    int d = qtr * 16 + t;
    for (int c = 0; c < 16; c++) s += pden[(bh * 16 + c) * 64 + d];
    rden[t] = 1.0f / s;
  }
  __syncthreads();
  int i = qtr * 1024 + t * 4;
  f32x4 s = {};
  for (int c = 0; c < 16; c++)
    s += *(const f32x4*)&pctx[((size_t)(bh * 16 + c)) * 4096 + i];
  s *= rden[t >> 4];
  *(f32x4*)&ctx[(size_t)bh * 4096 + i] = s;
}

// ---------------- attn_out = softmax(q)*DH^-.5 @ ctx -> bf16 ---------------
// Thread-per-row; ctx staged as padded f32x4 (broadcast b128 reads).
__global__ __launch_bounds__(256)
void attn_kernel(const bf16* __restrict__ qkv, const float* __restrict__ ctx,
                 bf16* __restrict__ attn)
{
  int blk = blockIdx.x;                  // bh*16 + chunk
  int chunk = blk & 15, bh = blk >> 4;
  int b = bh >> 4, h = bh & 15;
  int t = threadIdx.x;
  __shared__ f32x4 cs4[64][17];
#pragma unroll
  for (int j = 0; j < 4; j++) {
    int e0 = j * 1024 + t * 4;
    cs4[e0 >> 6][(e0 & 63) >> 2] = *(const f32x4*)&ctx[(size_t)bh * 4096 + e0];
  }
  __syncthreads();

  int s = chunk * 256 + t;
  const unsigned short* qp = (const unsigned short*)qkv + ((size_t)(b * S_ + s) * N3_ + h * DH_);
  float p[64];
#pragma unroll
  for (int j = 0; j < 8; j++) {
    bf16x8 q8 = *(const bf16x8*)(qp + j * 8);
#pragma unroll
    for (int i = 0; i < 8; i++) p[j * 8 + i] = bf2f(q8[i]);
  }
  float mx = p[0];
#pragma unroll
  for (int d = 1; d < 64; d++) mx = fmaxf(mx, p[d]);
  float sum = 0.0f;
#pragma unroll
  for (int d = 0; d < 64; d++) { p[d] = __expf(p[d] - mx); sum += p[d]; }
  float f = 0.125f / sum;      // DH^-0.5 = 0.125

  unsigned short* op = (unsigned short*)attn + ((size_t)(b * S_ + s) * D_ + h * DH_);
  for (int ec = 0; ec < 4; ec++) {
    f32x4 a0 = {}, a1 = {}, a2 = {}, a3 = {};
#pragma unroll
    for (int d = 0; d < 64; d++) {
      float pd = p[d];
      a0 += pd * cs4[d][ec * 4 + 0];
      a1 += pd * cs4[d][ec * 4 + 1];
      a2 += pd * cs4[d][ec * 4 + 2];
      a3 += pd * cs4[d][ec * 4 + 3];
    }
    bf16x8 o0, o1;
#pragma unroll
    for (int i = 0; i < 4; i++) {
      bf16 v0 = __float2bfloat16(a0[i] * f); o0[i] = *(short*)&v0;
      bf16 v1 = __float2bfloat16(a1[i] * f); o0[4 + i] = *(short*)&v1;
      bf16 v2 = __float2bfloat16(a2[i] * f); o1[i] = *(short*)&v2;
      bf16 v3 = __float2bfloat16(a3[i] * f); o1[4 + i] = *(short*)&v3;
    }
    *(bf16x8*)(op + ec * 16) = o0;
    *(bf16x8*)(op + ec * 16 + 8) = o1;
  }
}

// ---------------- ws layout (bytes) — total 160 MiB -------------------------
// weights [0,12M) | pden/ctx/pctx [12M,31M) | h/attn [32M,64M) |
// qkv [64M,160M); after qkv dead: x2b [64M,96M), y [96M,128M), z [128M,160M)
#define OFF_WQKVT  ((size_t)0)
#define OFF_WOT    ((size_t)6291456)
#define OFF_W1T    ((size_t)8388608)
#define OFF_W2T    ((size_t)10485760)
#define OFF_PDEN   ((size_t)12582912)
#define OFF_CTX    ((size_t)13139968)
#define OFF_PCTX   ((size_t)14680064)
#define OFF_H      ((size_t)33554432)
#define OFF_ATTN   OFF_H
#define OFF_QKV    ((size_t)67108864)
#define OFF_X2B    ((size_t)67108864)
#define OFF_Y      ((size_t)100663296)
#define OFF_Z      ((size_t)134217728)

extern "C" void kernel_launch(void* const* d_in, const int* in_sizes, int n_in,
                              void* d_out, int out_size, void* d_ws, size_t ws_size,
                              hipStream_t stream)
{
  const float* x     = (const float*)d_in[0];
  const float* ln1_g = (const float*)d_in[1];
  const float* ln1_b = (const float*)d_in[2];
  const float* Wqkv  = (const float*)d_in[3];
  const float* Wo    = (const float*)d_in[4];
  const float* bo    = (const float*)d_in[5];
  const float* ln2_g = (const float*)d_in[6];
  const float* ln2_b = (const float*)d_in[7];
  const float* W1    = (const float*)d_in[8];
  const float* b1    = (const float*)d_in[9];
  const float* W2    = (const float*)d_in[10];
  const float* b2    = (const float*)d_in[11];
  float* out = (float*)d_out;
  char* ws = (char*)d_ws;

  bf16*  h     = (bf16*)(ws + OFF_H);
  bf16*  qkv   = (bf16*)(ws + OFF_QKV);
  bf16*  attn  = (bf16*)(ws + OFF_ATTN);
  bf16*  x2b   = (bf16*)(ws + OFF_X2B);     // bf16 residual stream
  bf16*  y     = (bf16*)(ws + OFF_Y);
  bf16*  z     = (bf16*)(ws + OFF_Z);
  bf16*  wqkvt = (bf16*)(ws + OFF_WQKVT);
  bf16*  wot   = (bf16*)(ws + OFF_WOT);
  bf16*  w1t   = (bf16*)(ws + OFF_W1T);
  bf16*  w2t   = (bf16*)(ws + OFF_W2T);
  float* pden  = (float*)(ws + OFF_PDEN);
  float* pctx  = (float*)(ws + OFF_PCTX);
  float* ctx   = (float*)(ws + OFF_CTX);

  const size_t GEMM_LDS = 131072;

  // weight prep (bf16, transposed to [N][K]) — single fused launch
  transpose_cast4<<<dim3(192, 32), 256, 0, stream>>>(Wqkv, Wo, W1, W2,
                                                     wqkvt, wot, w1t, w2t);

  // LN1 + positional encoding
  ln_kernel<true, false><<<BS_, 256, 0, stream>>>(x, nullptr, ln1_g, ln1_b, h);

  // qkv = h @ Wqkv   (bf16 out)
  gemm256<EPI_BF16><<<(N3_ / 256) * (BS_ / 256), 512, GEMM_LDS, stream>>>(
      h, wqkvt, nullptr, qkv, nullptr, nullptr, nullptr, BS_, N3_, D_);

  // ctx numerator/denominator + merge
  ctx_partial<<<1024, 256, 0, stream>>>(qkv, pctx, pden);
  ctx_merge<<<256, 256, 0, stream>>>(pctx, pden, ctx);

  // attn_out (q-softmax fused), thread-per-row
  attn_kernel<<<1024, 256, 0, stream>>>(qkv, ctx, attn);

  // x2 = attn @ Wo + bo + x   (bf16 residual stream)
  gemm256<EPI_BIAS_RES_BF16><<<(D_ / 256) * (BS_ / 256), 512, GEMM_LDS, stream>>>(
      attn, wot, nullptr, x2b, bo, x, nullptr, BS_, D_, D_);

  // y = LN2(x2)
  ln_kernel<false, true><<<BS_, 256, 0, stream>>>(nullptr, x2b, ln2_g, ln2_b, y);

  // z = gelu(y @ W1 + b1)
  gemm256<EPI_BIAS_GELU_BF16><<<(D_ / 256) * (BS_ / 256), 512, GEMM_LDS, stream>>>(
      y, w1t, nullptr, z, b1, nullptr, nullptr, BS_, D_, D_);

  // out = z @ W2 + b2 + x2
  gemm256<EPI_BIAS_RESB_F32><<<(D_ / 256) * (BS_ / 256), 512, GEMM_LDS, stream>>>(
      z, w2t, out, nullptr, b2, nullptr, x2b, BS_, D_, D_);
}

// Round 8
// 383.020 us; speedup vs baseline: 1.3295x; 1.3295x over previous
//
#include <hip/hip_runtime.h>
#include <hip/hip_bf16.h>
#include <math.h>

#define B_   4
#define S_   4096
#define D_   1024
#define H_   16
#define DH_  64
#define BS_  (B_ * S_)     // 16384 rows
#define N3_  3072          // 3 * INNER

using bf16 = __hip_bfloat16;
typedef __attribute__((ext_vector_type(8))) short bf16x8;
typedef __attribute__((ext_vector_type(4))) float f32x4;

#define GAS __attribute__((address_space(1)))
#define LAS __attribute__((address_space(3)))

__device__ __forceinline__ void gload_lds16(const bf16* g, bf16* l) {
  __builtin_amdgcn_global_load_lds((const GAS void*)g, (LAS void*)l, 16, 0, 0);
}

__device__ __forceinline__ float bf2f(short u) {
  unsigned int x = ((unsigned int)(unsigned short)u) << 16;
  return __builtin_bit_cast(float, x);
}
__device__ __forceinline__ unsigned short f2bfu(float f) {
  bf16 t = __float2bfloat16(f);
  return *(unsigned short*)&t;
}

// ------------- fused weight cast+transpose: all 4 weights, one launch ------
__global__ __launch_bounds__(256)
void transpose_cast4(const float* __restrict__ Wqkv, const float* __restrict__ Wo,
                     const float* __restrict__ W1, const float* __restrict__ W2,
                     bf16* __restrict__ wqkvt, bf16* __restrict__ wot,
                     bf16* __restrict__ w1t, bf16* __restrict__ w2t)
{
  __shared__ float tile[32][33];
  int gx = blockIdx.x;
  const float* W; bf16* Wt; int N, xo;
  if (gx < 96)        { W = Wqkv; Wt = wqkvt; N = N3_; xo = gx; }
  else if (gx < 128)  { W = Wo;   Wt = wot;   N = D_;  xo = gx - 96; }
  else if (gx < 160)  { W = W1;   Wt = w1t;   N = D_;  xo = gx - 128; }
  else                { W = W2;   Wt = w2t;   N = D_;  xo = gx - 160; }
  int n0 = xo * 32, k0 = blockIdx.y * 32;
  int tx = threadIdx.x & 31, ty = threadIdx.x >> 5;   // 32 x 8
#pragma unroll
  for (int j = 0; j < 32; j += 8)
    tile[ty + j][tx] = W[(size_t)(k0 + ty + j) * N + n0 + tx];
  __syncthreads();
#pragma unroll
  for (int j = 0; j < 32; j += 8)
    Wt[(size_t)(n0 + ty + j) * 1024 + k0 + tx] = __float2bfloat16(tile[tx][ty + j]);
}

// ---------------- LayerNorm (+ optional PE), fp32 or bf16 input -> bf16 ----
template<bool PE, bool INBF16>
__global__ __launch_bounds__(256)
void ln_kernel(const float* __restrict__ Xf, const bf16* __restrict__ Xb,
               const float* __restrict__ G, const float* __restrict__ Bv,
               bf16* __restrict__ out)
{
  int row = blockIdx.x;                // b*S + s
  int t = threadIdx.x;
  float4 v;
  if (INBF16) {
    ushort4 u = ((const ushort4*)Xb)[(size_t)row * (D_ / 4) + t];
    v.x = bf2f(u.x); v.y = bf2f(u.y); v.z = bf2f(u.z); v.w = bf2f(u.w);
  } else {
    v = ((const float4*)(Xf + (size_t)row * D_))[t];
  }
  float s  = v.x + v.y + v.z + v.w;
  float ss = v.x * v.x + v.y * v.y + v.z * v.z + v.w * v.w;
#pragma unroll
  for (int o = 32; o > 0; o >>= 1) { s += __shfl_xor(s, o); ss += __shfl_xor(ss, o); }
  __shared__ float red[8];
  int wid = t >> 6, lane = t & 63;
  if (lane == 0) { red[wid] = s; red[4 + wid] = ss; }
  __syncthreads();
  s  = red[0] + red[1] + red[2] + red[3];
  ss = red[4] + red[5] + red[6] + red[7];
  float mean = s * (1.0f / D_);
  float var  = ss * (1.0f / D_) - mean * mean;
  float rs   = rsqrtf(var + 1e-6f);
  int d0 = t * 4;
  const float4 g4 = ((const float4*)G)[t];
  const float4 b4 = ((const float4*)Bv)[t];
  float o0 = (v.x - mean) * rs * g4.x + b4.x;
  float o1 = (v.y - mean) * rs * g4.y + b4.y;
  float o2 = (v.z - mean) * rs * g4.z + b4.z;
  float o3 = (v.w - mean) * rs * g4.w + b4.w;
  if (PE) {
    const float C = -0.0089944730194f;   // -ln(10000)/1024
    float p = (float)(row & (S_ - 1));
    float sn, cs;
    __sincosf(p * __expf((float)d0 * C), &sn, &cs);        o0 += sn; o1 += cs;
    __sincosf(p * __expf((float)(d0 + 2) * C), &sn, &cs);  o2 += sn; o3 += cs;
  }
  ushort4 pk;
  pk.x = f2bfu(o0); pk.y = f2bfu(o1); pk.z = f2bfu(o2); pk.w = f2bfu(o3);
  ((ushort4*)out)[(size_t)row * (D_ / 4) + t] = pk;
}

// ---------------- 256x256 8-phase bf16 MFMA GEMM ---------------------------
// Proven core (r5/r6): T2 LDS swizzle (conflicts=0), T1 2D-chunk XCD swizzle,
// counted vmcnt(4), setprio. New: EPI_QKV scatter epilogue (q head-major,
// k/v transposed) and AHM A-staging (head-major attn input for Wo).
enum { EPI_QKV = 0, EPI_BIAS_RES_BF16 = 1, EPI_BIAS_GELU_BF16 = 2, EPI_BIAS_RESB_F32 = 3 };

#define MFMA_ __builtin_amdgcn_mfma_f32_16x16x32_bf16

template<int EPI, bool AHM>
__global__ __launch_bounds__(512)
void gemm256(const bf16* __restrict__ A, const bf16* __restrict__ Bt,
             float* __restrict__ Cf, bf16* __restrict__ Cb,
             const float* __restrict__ bias, const float* __restrict__ resf,
             const bf16* __restrict__ resb,
             bf16* __restrict__ Ck, bf16* __restrict__ Cv,
             int M, int N, int K)
{
  extern __shared__ __align__(16) char smem[];
  bf16* lds = (bf16*)smem;

  const int t = threadIdx.x;
  const int wid = t >> 6, lane = t & 63;
  const int wr = wid >> 2, wc = wid & 3;        // 2 x 4 waves
  // XCD-aware 2D-chunked swizzle (nty==64, ntx%4==0, grid%8==0)
  const int bid = blockIdx.x;
  const int c = bid & 7;
  const int w = bid >> 3;
  const int sst = w >> 4;
  const int ii = w & 15;
  const int txg = sst >> 1, tyg = sst & 1;
  const int iy = ii & 3, ix = ii >> 2;
  const int ty = c * 8 + tyg * 4 + iy;
  const int tx = txg * 4 + ix;
  const int m0 = ty << 8, n0 = tx << 8;

  const bf16* Ab = AHM
      ? A + (((size_t)(m0 >> 12) * 16) * 4096 + (m0 & 4095)) * 64
      : A + (size_t)m0 * K;
  const bf16* Bb = Bt + (size_t)n0 * K;

  const int srow = t >> 2;
  const int scol = (((t & 3) ^ ((t >> 3) & 3)) * 8);
  const int NT = K >> 6;
  const int fr = lane & 15;
  const int fksw = (((lane >> 4) ^ ((lane >> 1) & 3)) * 8);

  f32x4 acc[8][4] = {};

  #define LDSHALF(b, mat, kh) (lds + (((((b) << 1) + (mat)) << 1) + (kh)) * 8192)

  #define STAGE(kt, mat, kh) do {                                              \
    bf16* _dst = LDSHALF((kt) & 1, (mat), (kh)) + t * 8;                       \
    const int _ktk = (kt) & (NT - 1);                                          \
    if ((mat) == 0 && AHM) {                                                   \
      const bf16* _sb = Ab + (size_t)_ktk * 262144 + (size_t)srow * 64         \
                        + (kh) * 32 + scol;                                    \
      gload_lds16(_sb, _dst);                                                  \
      gload_lds16(_sb + 8192, _dst + 4096);                                    \
    } else {                                                                   \
      const bf16* _sb = ((mat) == 0 ? Ab : Bb) + (size_t)srow * K              \
                        + (_ktk << 6) + (kh) * 32 + scol;                      \
      gload_lds16(_sb, _dst);                                                  \
      gload_lds16(_sb + (size_t)128 * K, _dst + 4096);                         \
    }                                                                          \
  } while (0)

  STAGE(0, 0, 0); STAGE(0, 1, 0);
  STAGE(0, 0, 1); STAGE(0, 1, 1);
  asm volatile("s_waitcnt vmcnt(4)" ::: "memory");
  __builtin_amdgcn_s_barrier();

#pragma unroll 2
  for (int kt = 0; kt < NT; ++kt) {
    const int cur = kt & 1;
    const bf16* hA0 = LDSHALF(cur, 0, 0);
    const bf16* hB0 = LDSHALF(cur, 1, 0);
    const bf16* hA1 = LDSHALF(cur, 0, 1);
    const bf16* hB1 = LDSHALF(cur, 1, 1);
    bf16x8 a[8], b0, b1, b2, b3;

    // ---- phase 1 ----
#pragma unroll
    for (int mi = 0; mi < 8; ++mi)
      a[mi] = *(const bf16x8*)&hA0[(wr * 128 + mi * 16 + fr) * 32 + fksw];
    b0 = *(const bf16x8*)&hB0[(wc * 64 +  0 + fr) * 32 + fksw];
    b1 = *(const bf16x8*)&hB0[(wc * 64 + 16 + fr) * 32 + fksw];
    STAGE(kt + 1, 0, 0);
    __builtin_amdgcn_s_barrier();
    __builtin_amdgcn_s_setprio(1);
#pragma unroll
    for (int mi = 0; mi < 8; ++mi) {
      acc[mi][0] = MFMA_(a[mi], b0, acc[mi][0], 0, 0, 0);
      acc[mi][1] = MFMA_(a[mi], b1, acc[mi][1], 0, 0, 0);
    }
    __builtin_amdgcn_s_setprio(0);
    __builtin_amdgcn_s_barrier();

    // ---- phase 2 ----
    b2 = *(const bf16x8*)&hB0[(wc * 64 + 32 + fr) * 32 + fksw];
    b3 = *(const bf16x8*)&hB0[(wc * 64 + 48 + fr) * 32 + fksw];
    STAGE(kt + 1, 1, 0);
    __builtin_amdgcn_s_barrier();
    __builtin_amdgcn_s_setprio(1);
#pragma unroll
    for (int mi = 0; mi < 8; ++mi) {
      acc[mi][2] = MFMA_(a[mi], b2, acc[mi][2], 0, 0, 0);
      acc[mi][3] = MFMA_(a[mi], b3, acc[mi][3], 0, 0, 0);
    }
    __builtin_amdgcn_s_setprio(0);
    asm volatile("s_waitcnt vmcnt(4)" ::: "memory");
    __builtin_amdgcn_s_barrier();

    // ---- phase 3 ----
#pragma unroll
    for (int mi = 0; mi < 8; ++mi)
      a[mi] = *(const bf16x8*)&hA1[(wr * 128 + mi * 16 + fr) * 32 + fksw];
    b0 = *(const bf16x8*)&hB1[(wc * 64 +  0 + fr) * 32 + fksw];
    b1 = *(const bf16x8*)&hB1[(wc * 64 + 16 + fr) * 32 + fksw];
    STAGE(kt + 1, 0, 1);
    __builtin_amdgcn_s_barrier();
    __builtin_amdgcn_s_setprio(1);
#pragma unroll
    for (int mi = 0; mi < 8; ++mi) {
      acc[mi][0] = MFMA_(a[mi], b0, acc[mi][0], 0, 0, 0);
      acc[mi][1] = MFMA_(a[mi], b1, acc[mi][1], 0, 0, 0);
    }
    __builtin_amdgcn_s_setprio(0);
    __builtin_amdgcn_s_barrier();

    // ---- phase 4 ----
    b2 = *(const bf16x8*)&hB1[(wc * 64 + 32 + fr) * 32 + fksw];
    b3 = *(const bf16x8*)&hB1[(wc * 64 + 48 + fr) * 32 + fksw];
    STAGE(kt + 1, 1, 1);
    __builtin_amdgcn_s_barrier();
    __builtin_amdgcn_s_setprio(1);
#pragma unroll
    for (int mi = 0; mi < 8; ++mi) {
      acc[mi][2] = MFMA_(a[mi], b2, acc[mi][2], 0, 0, 0);
      acc[mi][3] = MFMA_(a[mi], b3, acc[mi][3], 0, 0, 0);
    }
    __builtin_amdgcn_s_setprio(0);
    asm volatile("s_waitcnt vmcnt(4)" ::: "memory");
    __builtin_amdgcn_s_barrier();
  }
  asm volatile("s_waitcnt vmcnt(0)" ::: "memory");

  // ---- epilogue ----
  const int brow = m0 >> 12;           // batch index (tiles never straddle b)
  const int mrow = m0 & 4095;          // s-base within batch
#pragma unroll
  for (int mi = 0; mi < 8; ++mi) {
    int rowb = m0 + wr * 128 + mi * 16 + (lane >> 4) * 4;
#pragma unroll
    for (int ni = 0; ni < 4; ++ni) {
      int col = n0 + wc * 64 + ni * 16 + fr;
      if (EPI == EPI_QKV) {
        int qsel = col >> 10;                 // block-uniform (256-col tiles)
        int hh = (col >> 6) & 15;
        int dd = col & 63;
        int sloc = mrow + wr * 128 + mi * 16 + (lane >> 4) * 4;
        if (qsel == 0) {
          unsigned short* qp = (unsigned short*)Cb +
            (((size_t)(brow * 16 + hh) * 4096 + sloc) * 64 + dd);
#pragma unroll
          for (int j = 0; j < 4; ++j)
            qp[(size_t)j * 64] = f2bfu(acc[mi][ni][j]);
        } else {
          unsigned short* kp = (unsigned short*)(qsel == 1 ? Ck : Cv) +
            (((size_t)(brow * 16 + hh) * 64 + dd) * 4096 + sloc);
          ushort4 pk;
          pk.x = f2bfu(acc[mi][ni][0]); pk.y = f2bfu(acc[mi][ni][1]);
          pk.z = f2bfu(acc[mi][ni][2]); pk.w = f2bfu(acc[mi][ni][3]);
          *(ushort4*)kp = pk;
        }
      } else {
#pragma unroll
        for (int j = 0; j < 4; ++j) {
          int row = rowb + j;
          float v = acc[mi][ni][j];
          if (EPI == EPI_BIAS_RES_BF16) {
            Cb[(size_t)row * N + col] =
              __float2bfloat16(v + bias[col] + resf[(size_t)row * N + col]);
          } else if (EPI == EPI_BIAS_GELU_BF16) {
            float u = v + bias[col];
            u = 0.5f * u * (1.0f + erff(u * 0.70710678118654752f));
            Cb[(size_t)row * N + col] = __float2bfloat16(u);
          } else {
            Cf[(size_t)row * N + col] =
              v + bias[col] + bf2f(*(const short*)&resb[(size_t)row * N + col]);
          }
        }
      }
    }
  }
  #undef STAGE
  #undef LDSHALF
}

// ---------------- ctx: ctxT[e<-cols? no: see below] ------------------------
// ctx[d][e] = sum_s exp(k[s][d]) * v[s][e] / den[d], via MFMA:
// A = exp(kT[d][s]) (M=d, K=s), B = v -> b-frag from vT[e][s]. One block/bh;
// 4 waves split K=4096. Output ctxT[e][d] bf16 (B-operand layout for attn).
__global__ __launch_bounds__(256)
void ctx_kernel(const bf16* __restrict__ kT, const bf16* __restrict__ vT,
                bf16* __restrict__ ctxT)
{
  int bh = blockIdx.x;
  int t = threadIdx.x, lane = t & 63, wid = t >> 6;
  __shared__ float partials[4][4096];   // 64 KiB, frag-major
  __shared__ float rden[64];
  __shared__ float denp[256];

  // den pass: thread (d = t>>2, part = t&3) sums 1024 exps
  {
    int d = t >> 2, part = t & 3;
    const unsigned short* kp = (const unsigned short*)kT +
      ((size_t)bh * 64 + d) * 4096 + part * 1024;
    float s = 0.f;
    for (int i = 0; i < 128; ++i) {
      bf16x8 k8 = *(const bf16x8*)(kp + i * 8);
#pragma unroll
      for (int j = 0; j < 8; ++j) s += __expf(bf2f(k8[j]));
    }
    denp[t] = s;
  }
  __syncthreads();
  if (t < 64) rden[t] = 1.0f / (denp[t*4] + denp[t*4+1] + denp[t*4+2] + denp[t*4+3]);

  // mfma: wave wid covers k in [wid*1024, +1024)
  const int fr = lane & 15, g = lane >> 4;
  f32x4 acc[4][4] = {};
  const unsigned short* kb = (const unsigned short*)kT + (size_t)bh * 64 * 4096;
  const unsigned short* vb = (const unsigned short*)vT + (size_t)bh * 64 * 4096;
  for (int i = 0; i < 32; ++i) {
    int kofs = wid * 1024 + i * 32 + g * 8;
    bf16x8 av[4], bv[4];
#pragma unroll
    for (int mi = 0; mi < 4; ++mi) {
      bf16x8 kr = *(const bf16x8*)(kb + (size_t)(mi * 16 + fr) * 4096 + kofs);
      bf16x8 ae;
#pragma unroll
      for (int j = 0; j < 8; ++j) ae[j] = (short)f2bfu(__expf(bf2f(kr[j])));
      av[mi] = ae;
      bv[mi] = *(const bf16x8*)(vb + (size_t)(mi * 16 + fr) * 4096 + kofs);
    }
#pragma unroll
    for (int mi = 0; mi < 4; ++mi)
#pragma unroll
      for (int ni = 0; ni < 4; ++ni)
        acc[mi][ni] = MFMA_(av[mi], bv[ni], acc[mi][ni], 0, 0, 0);
  }
#pragma unroll
  for (int mi = 0; mi < 4; ++mi)
#pragma unroll
    for (int ni = 0; ni < 4; ++ni)
      *(f32x4*)&partials[wid][(mi * 4 + ni) * 256 + lane * 4] = acc[mi][ni];
  __syncthreads();

  // reduce across waves + normalize + store ctxT[e][d] (ushort4)
  int lane2 = t & 63, fg = t >> 6;
  int fr2 = lane2 & 15, g2 = lane2 >> 4;
#pragma unroll
  for (int ff = 0; ff < 4; ++ff) {
    int f = fg * 4 + ff;
    int mi = f >> 2, ni = f & 3;
    f32x4 s = {};
#pragma unroll
    for (int ww = 0; ww < 4; ++ww)
      s += *(const f32x4*)&partials[ww][f * 256 + lane2 * 4];
    int e = ni * 16 + fr2;
    int d0 = mi * 16 + g2 * 4;
    ushort4 pk;
    pk.x = f2bfu(s[0] * rden[d0 + 0]);
    pk.y = f2bfu(s[1] * rden[d0 + 1]);
    pk.z = f2bfu(s[2] * rden[d0 + 2]);
    pk.w = f2bfu(s[3] * rden[d0 + 3]);
    *(ushort4*)((unsigned short*)ctxT + ((size_t)bh * 64 + e) * 64 + d0) = pk;
  }
}

// ---------------- attn: softmax(q)*DH^-.5 @ ctx -> attn_hm, MFMA -----------
// Block = (bh, 256 rows). Thread-per-row softmax -> P bf16 in XOR-swizzled
// LDS (pos = blk ^ (row&7), 2-way max per quarter-wave). ctxT staged same.
// Each wave: its 64 rows, 4x4 tiles x 2 k-steps = 32 mfma.
__global__ __launch_bounds__(256)
void attn_kernel(const bf16* __restrict__ qhm, const bf16* __restrict__ ctxT,
                 bf16* __restrict__ attn)
{
  int blk = blockIdx.x;           // bh*16 + chunk
  int chunk = blk & 15, bh = blk >> 4;
  int t = threadIdx.x, lane = t & 63, wid = t >> 6;
  __shared__ bf16 P[256 * 64];    // 32 KiB: [wave region][row][8 blk x 8]
  __shared__ bf16 CT[64 * 64];    // 8 KiB:  [e][8 blk x 8]

  // stage ctxT (swizzled)
  {
    const unsigned short* cg = (const unsigned short*)ctxT + (size_t)bh * 4096;
#pragma unroll
    for (int r = 0; r < 2; ++r) {
      int idx = r * 256 + t;                 // 16B-chunk index
      int e = idx >> 3, b = idx & 7;
      bf16x8 v = *(const bf16x8*)(cg + idx * 8);
      *(bf16x8*)&CT[e * 64 + ((b ^ (e & 7)) * 8)] = v;
    }
  }
  // q softmax, thread-per-row
  {
    int s = chunk * 256 + t;
    const unsigned short* qp = (const unsigned short*)qhm + ((size_t)bh * 4096 + s) * 64;
    float p[64];
#pragma unroll
    for (int j = 0; j < 8; ++j) {
      bf16x8 q8 = *(const bf16x8*)(qp + j * 8);
#pragma unroll
      for (int i = 0; i < 8; ++i) p[j * 8 + i] = bf2f(q8[i]);
    }
    float mx = p[0];
#pragma unroll
    for (int d = 1; d < 64; ++d) mx = fmaxf(mx, p[d]);
    float sum = 0.f;
#pragma unroll
    for (int d = 0; d < 64; ++d) { p[d] = __expf(p[d] - mx); sum += p[d]; }
    float f = 0.125f / sum;       // DH^-0.5
    bf16* pb = &P[(t >> 6) * 4096 + (t & 63) * 64];
#pragma unroll
    for (int b = 0; b < 8; ++b) {
      bf16x8 pk;
#pragma unroll
      for (int i = 0; i < 8; ++i) pk[i] = (short)f2bfu(p[b * 8 + i] * f);
      *(bf16x8*)&pb[((b ^ (t & 7)) * 8)] = pk;
    }
  }
  __syncthreads();

  // mfma: wave computes its 64 rows x 64 cols
  const int fr = lane & 15, g = lane >> 4;
  f32x4 acc[4][4] = {};
  const bf16* Pw = &P[wid * 4096];
#pragma unroll
  for (int ks = 0; ks < 2; ++ks) {
    bf16x8 av[4], bv[4];
#pragma unroll
    for (int mi = 0; mi < 4; ++mi) {
      int r = mi * 16 + fr;
      av[mi] = *(const bf16x8*)&Pw[r * 64 + (((ks * 4 + g) ^ (r & 7)) * 8)];
    }
#pragma unroll
    for (int ni = 0; ni < 4; ++ni) {
      int e = ni * 16 + fr;
      bv[ni] = *(const bf16x8*)&CT[e * 64 + (((ks * 4 + g) ^ (e & 7)) * 8)];
    }
#pragma unroll
    for (int mi = 0; mi < 4; ++mi)
#pragma unroll
      for (int ni = 0; ni < 4; ++ni)
        acc[mi][ni] = MFMA_(av[mi], bv[ni], acc[mi][ni], 0, 0, 0);
  }
  // store attn_hm[bh][s][e]
  unsigned short* ob = (unsigned short*)attn +
      ((size_t)bh * 4096 + chunk * 256 + wid * 64) * 64;
#pragma unroll
  for (int mi = 0; mi < 4; ++mi)
#pragma unroll
    for (int ni = 0; ni < 4; ++ni) {
      int e = ni * 16 + fr;
#pragma unroll
      for (int j = 0; j < 4; ++j) {
        int r = mi * 16 + g * 4 + j;
        ob[(size_t)r * 64 + e] = f2bfu(acc[mi][ni][j]);
      }
    }
}

// ---------------- ws layout (bytes) — total 160 MiB -------------------------
// weights [0,12M) | ctxT [12M,12.5M) | attn_hm [32M,64M) |
// q_hm [64M,96M) | kT [96M,128M) | vT [128M,160M)
// after attn: z over q_hm; x2b over kT; y over vT
#define OFF_WQKVT  ((size_t)0)
#define OFF_WOT    ((size_t)6291456)
#define OFF_W1T    ((size_t)8388608)
#define OFF_W2T    ((size_t)10485760)
#define OFF_CTXT   ((size_t)12582912)
#define OFF_ATTN   ((size_t)33554432)
#define OFF_H      OFF_ATTN
#define OFF_QHM    ((size_t)67108864)
#define OFF_KT     ((size_t)100663296)
#define OFF_VT     ((size_t)134217728)
#define OFF_Z      OFF_QHM
#define OFF_X2B    OFF_KT
#define OFF_Y      OFF_VT

extern "C" void kernel_launch(void* const* d_in, const int* in_sizes, int n_in,
                              void* d_out, int out_size, void* d_ws, size_t ws_size,
                              hipStream_t stream)
{
  const float* x     = (const float*)d_in[0];
  const float* ln1_g = (const float*)d_in[1];
  const float* ln1_b = (const float*)d_in[2];
  const float* Wqkv  = (const float*)d_in[3];
  const float* Wo    = (const float*)d_in[4];
  const float* bo    = (const float*)d_in[5];
  const float* ln2_g = (const float*)d_in[6];
  const float* ln2_b = (const float*)d_in[7];
  const float* W1    = (const float*)d_in[8];
  const float* b1    = (const float*)d_in[9];
  const float* W2    = (const float*)d_in[10];
  const float* b2    = (const float*)d_in[11];
  float* out = (float*)d_out;
  char* ws = (char*)d_ws;

  bf16*  h     = (bf16*)(ws + OFF_H);       // LN1 out (dead after qkv gemm)
  bf16*  attn  = (bf16*)(ws + OFF_ATTN);
  bf16*  qhm   = (bf16*)(ws + OFF_QHM);
  bf16*  kT    = (bf16*)(ws + OFF_KT);
  bf16*  vT    = (bf16*)(ws + OFF_VT);
  bf16*  ctxT  = (bf16*)(ws + OFF_CTXT);
  bf16*  x2b   = (bf16*)(ws + OFF_X2B);
  bf16*  y     = (bf16*)(ws + OFF_Y);
  bf16*  z     = (bf16*)(ws + OFF_Z);
  bf16*  wqkvt = (bf16*)(ws + OFF_WQKVT);
  bf16*  wot   = (bf16*)(ws + OFF_WOT);
  bf16*  w1t   = (bf16*)(ws + OFF_W1T);
  bf16*  w2t   = (bf16*)(ws + OFF_W2T);

  const size_t GEMM_LDS = 131072;

  transpose_cast4<<<dim3(192, 32), 256, 0, stream>>>(Wqkv, Wo, W1, W2,
                                                     wqkvt, wot, w1t, w2t);

  ln_kernel<true, false><<<BS_, 256, 0, stream>>>(x, nullptr, ln1_g, ln1_b, h);

  // qkv gemm: scatter epilogue -> q_hm, kT, vT
  gemm256<EPI_QKV, false><<<(N3_ / 256) * (BS_ / 256), 512, GEMM_LDS, stream>>>(
      h, wqkvt, nullptr, qhm, nullptr, nullptr, nullptr, kT, vT, BS_, N3_, D_);

  // ctx (MFMA) -> ctxT bf16
  ctx_kernel<<<64, 256, 0, stream>>>(kT, vT, ctxT);

  // attn (MFMA) -> attn_hm
  attn_kernel<<<1024, 256, 0, stream>>>(qhm, ctxT, attn);

  // x2 = attn @ Wo + bo + x  (AHM staging from head-major attn)
  gemm256<EPI_BIAS_RES_BF16, true><<<(D_ / 256) * (BS_ / 256), 512, GEMM_LDS, stream>>>(
      attn, wot, nullptr, x2b, bo, x, nullptr, nullptr, nullptr, BS_, D_, D_);

  ln_kernel<false, true><<<BS_, 256, 0, stream>>>(nullptr, x2b, ln2_g, ln2_b, y);

  gemm256<EPI_BIAS_GELU_BF16, false><<<(D_ / 256) * (BS_ / 256), 512, GEMM_LDS, stream>>>(
      y, w1t, nullptr, z, b1, nullptr, nullptr, nullptr, nullptr, BS_, D_, D_);

  gemm256<EPI_BIAS_RESB_F32, false><<<(D_ / 256) * (BS_ / 256), 512, GEMM_LDS, stream>>>(
      z, w2t, out, nullptr, b2, nullptr, x2b, nullptr, nullptr, BS_, D_, D_);
}

// Round 9
// 353.597 us; speedup vs baseline: 1.4401x; 1.0832x over previous
//
#include <hip/hip_runtime.h>
#include <hip/hip_bf16.h>
#include <math.h>

#define B_   4
#define S_   4096
#define D_   1024
#define H_   16
#define DH_  64
#define BS_  (B_ * S_)     // 16384 rows
#define N3_  3072          // 3 * INNER

using bf16 = __hip_bfloat16;
typedef __attribute__((ext_vector_type(8))) short bf16x8;
typedef __attribute__((ext_vector_type(4))) float f32x4;

#define GAS __attribute__((address_space(1)))
#define LAS __attribute__((address_space(3)))

__device__ __forceinline__ void gload_lds16(const bf16* g, bf16* l) {
  __builtin_amdgcn_global_load_lds((const GAS void*)g, (LAS void*)l, 16, 0, 0);
}

__device__ __forceinline__ float bf2f(short u) {
  unsigned int x = ((unsigned int)(unsigned short)u) << 16;
  return __builtin_bit_cast(float, x);
}
__device__ __forceinline__ unsigned short f2bfu(float f) {
  bf16 t = __float2bfloat16(f);
  return *(unsigned short*)&t;
}

// ------------- fused weight cast+transpose: all 4 weights, one launch ------
__global__ __launch_bounds__(256)
void transpose_cast4(const float* __restrict__ Wqkv, const float* __restrict__ Wo,
                     const float* __restrict__ W1, const float* __restrict__ W2,
                     bf16* __restrict__ wqkvt, bf16* __restrict__ wot,
                     bf16* __restrict__ w1t, bf16* __restrict__ w2t)
{
  __shared__ float tile[32][33];
  int gx = blockIdx.x;
  const float* W; bf16* Wt; int N, xo;
  if (gx < 96)        { W = Wqkv; Wt = wqkvt; N = N3_; xo = gx; }
  else if (gx < 128)  { W = Wo;   Wt = wot;   N = D_;  xo = gx - 96; }
  else if (gx < 160)  { W = W1;   Wt = w1t;   N = D_;  xo = gx - 128; }
  else                { W = W2;   Wt = w2t;   N = D_;  xo = gx - 160; }
  int n0 = xo * 32, k0 = blockIdx.y * 32;
  int tx = threadIdx.x & 31, ty = threadIdx.x >> 5;   // 32 x 8
#pragma unroll
  for (int j = 0; j < 32; j += 8)
    tile[ty + j][tx] = W[(size_t)(k0 + ty + j) * N + n0 + tx];
  __syncthreads();
#pragma unroll
  for (int j = 0; j < 32; j += 8)
    Wt[(size_t)(n0 + ty + j) * 1024 + k0 + tx] = __float2bfloat16(tile[tx][ty + j]);
}

// ---------------- LayerNorm (+ optional PE), fp32 or bf16 input -> bf16 ----
template<bool PE, bool INBF16>
__global__ __launch_bounds__(256)
void ln_kernel(const float* __restrict__ Xf, const bf16* __restrict__ Xb,
               const float* __restrict__ G, const float* __restrict__ Bv,
               bf16* __restrict__ out)
{
  int row = blockIdx.x;                // b*S + s
  int t = threadIdx.x;
  float4 v;
  if (INBF16) {
    ushort4 u = ((const ushort4*)Xb)[(size_t)row * (D_ / 4) + t];
    v.x = bf2f(u.x); v.y = bf2f(u.y); v.z = bf2f(u.z); v.w = bf2f(u.w);
  } else {
    v = ((const float4*)(Xf + (size_t)row * D_))[t];
  }
  float s  = v.x + v.y + v.z + v.w;
  float ss = v.x * v.x + v.y * v.y + v.z * v.z + v.w * v.w;
#pragma unroll
  for (int o = 32; o > 0; o >>= 1) { s += __shfl_xor(s, o); ss += __shfl_xor(ss, o); }
  __shared__ float red[8];
  int wid = t >> 6, lane = t & 63;
  if (lane == 0) { red[wid] = s; red[4 + wid] = ss; }
  __syncthreads();
  s  = red[0] + red[1] + red[2] + red[3];
  ss = red[4] + red[5] + red[6] + red[7];
  float mean = s * (1.0f / D_);
  float var  = ss * (1.0f / D_) - mean * mean;
  float rs   = rsqrtf(var + 1e-6f);
  int d0 = t * 4;
  const float4 g4 = ((const float4*)G)[t];
  const float4 b4 = ((const float4*)Bv)[t];
  float o0 = (v.x - mean) * rs * g4.x + b4.x;
  float o1 = (v.y - mean) * rs * g4.y + b4.y;
  float o2 = (v.z - mean) * rs * g4.z + b4.z;
  float o3 = (v.w - mean) * rs * g4.w + b4.w;
  if (PE) {
    const float C = -0.0089944730194f;   // -ln(10000)/1024
    float p = (float)(row & (S_ - 1));
    float sn, cs;
    __sincosf(p * __expf((float)d0 * C), &sn, &cs);        o0 += sn; o1 += cs;
    __sincosf(p * __expf((float)(d0 + 2) * C), &sn, &cs);  o2 += sn; o3 += cs;
  }
  ushort4 pk;
  pk.x = f2bfu(o0); pk.y = f2bfu(o1); pk.z = f2bfu(o2); pk.w = f2bfu(o3);
  ((ushort4*)out)[(size_t)row * (D_ / 4) + t] = pk;
}

// ---------------- 256x256 8-phase bf16 MFMA GEMM ---------------------------
// Proven core (r5/r6): T2 LDS swizzle (conflicts=0), T1 2D-chunk XCD swizzle,
// counted vmcnt(4), setprio. EPI_QKV scatter epilogue (q head-major, k/v
// transposed); AHM A-staging (head-major attn input for Wo).
enum { EPI_QKV = 0, EPI_BIAS_RES_BF16 = 1, EPI_BIAS_GELU_BF16 = 2, EPI_BIAS_RESB_F32 = 3 };

#define MFMA_ __builtin_amdgcn_mfma_f32_16x16x32_bf16

template<int EPI, bool AHM>
__global__ __launch_bounds__(512)
void gemm256(const bf16* __restrict__ A, const bf16* __restrict__ Bt,
             float* __restrict__ Cf, bf16* __restrict__ Cb,
             const float* __restrict__ bias, const float* __restrict__ resf,
             const bf16* __restrict__ resb,
             bf16* __restrict__ Ck, bf16* __restrict__ Cv,
             int M, int N, int K)
{
  extern __shared__ __align__(16) char smem[];
  bf16* lds = (bf16*)smem;

  const int t = threadIdx.x;
  const int wid = t >> 6, lane = t & 63;
  const int wr = wid >> 2, wc = wid & 3;        // 2 x 4 waves
  // XCD-aware 2D-chunked swizzle (nty==64, ntx%4==0, grid%8==0)
  const int bid = blockIdx.x;
  const int c = bid & 7;
  const int w = bid >> 3;
  const int sst = w >> 4;
  const int ii = w & 15;
  const int txg = sst >> 1, tyg = sst & 1;
  const int iy = ii & 3, ix = ii >> 2;
  const int ty = c * 8 + tyg * 4 + iy;
  const int tx = txg * 4 + ix;
  const int m0 = ty << 8, n0 = tx << 8;

  const bf16* Ab = AHM
      ? A + (((size_t)(m0 >> 12) * 16) * 4096 + (m0 & 4095)) * 64
      : A + (size_t)m0 * K;
  const bf16* Bb = Bt + (size_t)n0 * K;

  const int srow = t >> 2;
  const int scol = (((t & 3) ^ ((t >> 3) & 3)) * 8);
  const int NT = K >> 6;
  const int fr = lane & 15;
  const int fksw = (((lane >> 4) ^ ((lane >> 1) & 3)) * 8);

  f32x4 acc[8][4] = {};

  #define LDSHALF(b, mat, kh) (lds + (((((b) << 1) + (mat)) << 1) + (kh)) * 8192)

  #define STAGE(kt, mat, kh) do {                                              \
    bf16* _dst = LDSHALF((kt) & 1, (mat), (kh)) + t * 8;                       \
    const int _ktk = (kt) & (NT - 1);                                          \
    if ((mat) == 0 && AHM) {                                                   \
      const bf16* _sb = Ab + (size_t)_ktk * 262144 + (size_t)srow * 64         \
                        + (kh) * 32 + scol;                                    \
      gload_lds16(_sb, _dst);                                                  \
      gload_lds16(_sb + 8192, _dst + 4096);                                    \
    } else {                                                                   \
      const bf16* _sb = ((mat) == 0 ? Ab : Bb) + (size_t)srow * K              \
                        + (_ktk << 6) + (kh) * 32 + scol;                      \
      gload_lds16(_sb, _dst);                                                  \
      gload_lds16(_sb + (size_t)128 * K, _dst + 4096);                         \
    }                                                                          \
  } while (0)

  STAGE(0, 0, 0); STAGE(0, 1, 0);
  STAGE(0, 0, 1); STAGE(0, 1, 1);
  asm volatile("s_waitcnt vmcnt(4)" ::: "memory");
  __builtin_amdgcn_s_barrier();

#pragma unroll 2
  for (int kt = 0; kt < NT; ++kt) {
    const int cur = kt & 1;
    const bf16* hA0 = LDSHALF(cur, 0, 0);
    const bf16* hB0 = LDSHALF(cur, 1, 0);
    const bf16* hA1 = LDSHALF(cur, 0, 1);
    const bf16* hB1 = LDSHALF(cur, 1, 1);
    bf16x8 a[8], b0, b1, b2, b3;

    // ---- phase 1 ----
#pragma unroll
    for (int mi = 0; mi < 8; ++mi)
      a[mi] = *(const bf16x8*)&hA0[(wr * 128 + mi * 16 + fr) * 32 + fksw];
    b0 = *(const bf16x8*)&hB0[(wc * 64 +  0 + fr) * 32 + fksw];
    b1 = *(const bf16x8*)&hB0[(wc * 64 + 16 + fr) * 32 + fksw];
    STAGE(kt + 1, 0, 0);
    __builtin_amdgcn_s_barrier();
    __builtin_amdgcn_s_setprio(1);
#pragma unroll
    for (int mi = 0; mi < 8; ++mi) {
      acc[mi][0] = MFMA_(a[mi], b0, acc[mi][0], 0, 0, 0);
      acc[mi][1] = MFMA_(a[mi], b1, acc[mi][1], 0, 0, 0);
    }
    __builtin_amdgcn_s_setprio(0);
    __builtin_amdgcn_s_barrier();

    // ---- phase 2 ----
    b2 = *(const bf16x8*)&hB0[(wc * 64 + 32 + fr) * 32 + fksw];
    b3 = *(const bf16x8*)&hB0[(wc * 64 + 48 + fr) * 32 + fksw];
    STAGE(kt + 1, 1, 0);
    __builtin_amdgcn_s_barrier();
    __builtin_amdgcn_s_setprio(1);
#pragma unroll
    for (int mi = 0; mi < 8; ++mi) {
      acc[mi][2] = MFMA_(a[mi], b2, acc[mi][2], 0, 0, 0);
      acc[mi][3] = MFMA_(a[mi], b3, acc[mi][3], 0, 0, 0);
    }
    __builtin_amdgcn_s_setprio(0);
    asm volatile("s_waitcnt vmcnt(4)" ::: "memory");
    __builtin_amdgcn_s_barrier();

    // ---- phase 3 ----
#pragma unroll
    for (int mi = 0; mi < 8; ++mi)
      a[mi] = *(const bf16x8*)&hA1[(wr * 128 + mi * 16 + fr) * 32 + fksw];
    b0 = *(const bf16x8*)&hB1[(wc * 64 +  0 + fr) * 32 + fksw];
    b1 = *(const bf16x8*)&hB1[(wc * 64 + 16 + fr) * 32 + fksw];
    STAGE(kt + 1, 0, 1);
    __builtin_amdgcn_s_barrier();
    __builtin_amdgcn_s_setprio(1);
#pragma unroll
    for (int mi = 0; mi < 8; ++mi) {
      acc[mi][0] = MFMA_(a[mi], b0, acc[mi][0], 0, 0, 0);
      acc[mi][1] = MFMA_(a[mi], b1, acc[mi][1], 0, 0, 0);
    }
    __builtin_amdgcn_s_setprio(0);
    __builtin_amdgcn_s_barrier();

    // ---- phase 4 ----
    b2 = *(const bf16x8*)&hB1[(wc * 64 + 32 + fr) * 32 + fksw];
    b3 = *(const bf16x8*)&hB1[(wc * 64 + 48 + fr) * 32 + fksw];
    STAGE(kt + 1, 1, 1);
    __builtin_amdgcn_s_barrier();
    __builtin_amdgcn_s_setprio(1);
#pragma unroll
    for (int mi = 0; mi < 8; ++mi) {
      acc[mi][2] = MFMA_(a[mi], b2, acc[mi][2], 0, 0, 0);
      acc[mi][3] = MFMA_(a[mi], b3, acc[mi][3], 0, 0, 0);
    }
    __builtin_amdgcn_s_setprio(0);
    asm volatile("s_waitcnt vmcnt(4)" ::: "memory");
    __builtin_amdgcn_s_barrier();
  }
  asm volatile("s_waitcnt vmcnt(0)" ::: "memory");

  // ---- epilogue ----
  const int brow = m0 >> 12;           // batch index (tiles never straddle b)
  const int mrow = m0 & 4095;          // s-base within batch
#pragma unroll
  for (int mi = 0; mi < 8; ++mi) {
    int rowb = m0 + wr * 128 + mi * 16 + (lane >> 4) * 4;
#pragma unroll
    for (int ni = 0; ni < 4; ++ni) {
      int col = n0 + wc * 64 + ni * 16 + fr;
      if (EPI == EPI_QKV) {
        int qsel = col >> 10;                 // block-uniform (256-col tiles)
        int hh = (col >> 6) & 15;
        int dd = col & 63;
        int sloc = mrow + wr * 128 + mi * 16 + (lane >> 4) * 4;
        if (qsel == 0) {
          unsigned short* qp = (unsigned short*)Cb +
            (((size_t)(brow * 16 + hh) * 4096 + sloc) * 64 + dd);
#pragma unroll
          for (int j = 0; j < 4; ++j)
            qp[(size_t)j * 64] = f2bfu(acc[mi][ni][j]);
        } else {
          unsigned short* kp = (unsigned short*)(qsel == 1 ? Ck : Cv) +
            (((size_t)(brow * 16 + hh) * 64 + dd) * 4096 + sloc);
          ushort4 pk;
          pk.x = f2bfu(acc[mi][ni][0]); pk.y = f2bfu(acc[mi][ni][1]);
          pk.z = f2bfu(acc[mi][ni][2]); pk.w = f2bfu(acc[mi][ni][3]);
          *(ushort4*)kp = pk;
        }
      } else {
#pragma unroll
        for (int j = 0; j < 4; ++j) {
          int row = rowb + j;
          float v = acc[mi][ni][j];
          if (EPI == EPI_BIAS_RES_BF16) {
            Cb[(size_t)row * N + col] =
              __float2bfloat16(v + bias[col] + resf[(size_t)row * N + col]);
          } else if (EPI == EPI_BIAS_GELU_BF16) {
            float u = v + bias[col];
            u = 0.5f * u * (1.0f + erff(u * 0.70710678118654752f));
            Cb[(size_t)row * N + col] = __float2bfloat16(u);
          } else {
            Cf[(size_t)row * N + col] =
              v + bias[col] + bf2f(*(const short*)&resb[(size_t)row * N + col]);
          }
        }
      }
    }
  }
  #undef STAGE
  #undef LDSHALF
}

// ---------------- ctx split-K partial: MFMA, den fused in-loop -------------
// Block = (bh, kc): k-slice of 512. A = exp(kT[d][s]) built in-reg (den summed
// from the same float exps), B = vT[e][s]. Cross-wave LDS reduce -> fp32
// partial frags + den partials.
__global__ __launch_bounds__(256)
void ctx_partial(const bf16* __restrict__ kT, const bf16* __restrict__ vT,
                 float* __restrict__ pctx, float* __restrict__ pden)
{
  int blk = blockIdx.x;          // bh*8 + kc
  int kc = blk & 7, bh = blk >> 3;
  int t = threadIdx.x, lane = t & 63, wid = t >> 6;
  const int fr = lane & 15, g = lane >> 4;
  __shared__ float part[4][4096];
  __shared__ float dpart[4][64];

  f32x4 acc[4][4] = {};
  float dsum[4] = {0.f, 0.f, 0.f, 0.f};
  const unsigned short* kb = (const unsigned short*)kT + (size_t)bh * 64 * 4096;
  const unsigned short* vb = (const unsigned short*)vT + (size_t)bh * 64 * 4096;
  const int kbase = kc * 512 + wid * 128;
#pragma unroll
  for (int i = 0; i < 4; ++i) {
    int kofs = kbase + i * 32 + g * 8;
    bf16x8 av[4], bv[4];
#pragma unroll
    for (int mi = 0; mi < 4; ++mi) {
      bf16x8 kr = *(const bf16x8*)(kb + (size_t)(mi * 16 + fr) * 4096 + kofs);
      bf16x8 ae;
      float es = 0.f;
#pragma unroll
      for (int j = 0; j < 8; ++j) {
        float e = __expf(bf2f(kr[j]));
        es += e;
        ae[j] = (short)f2bfu(e);
      }
      dsum[mi] += es;
      av[mi] = ae;
      bv[mi] = *(const bf16x8*)(vb + (size_t)(mi * 16 + fr) * 4096 + kofs);
    }
#pragma unroll
    for (int mi = 0; mi < 4; ++mi)
#pragma unroll
      for (int ni = 0; ni < 4; ++ni)
        acc[mi][ni] = MFMA_(av[mi], bv[ni], acc[mi][ni], 0, 0, 0);
  }
  // den: lanes {fr, fr+16, fr+32, fr+48} hold disjoint k-slices of d=mi*16+fr
#pragma unroll
  for (int mi = 0; mi < 4; ++mi) {
    dsum[mi] += __shfl_xor(dsum[mi], 16);
    dsum[mi] += __shfl_xor(dsum[mi], 32);
  }
#pragma unroll
  for (int mi = 0; mi < 4; ++mi)
#pragma unroll
    for (int ni = 0; ni < 4; ++ni)
      *(f32x4*)&part[wid][(mi * 4 + ni) * 256 + lane * 4] = acc[mi][ni];
  if (g == 0) {
#pragma unroll
    for (int mi = 0; mi < 4; ++mi) dpart[wid][mi * 16 + fr] = dsum[mi];
  }
  __syncthreads();
  int lane2 = t & 63, fg = t >> 6;
#pragma unroll
  for (int ff = 0; ff < 4; ++ff) {
    int f = fg * 4 + ff;
    f32x4 s = {};
#pragma unroll
    for (int ww = 0; ww < 4; ++ww)
      s += *(const f32x4*)&part[ww][f * 256 + lane2 * 4];
    *(f32x4*)&pctx[((size_t)blk * 16 + f) * 256 + lane2 * 4] = s;
  }
  if (t < 64)
    pden[blk * 64 + t] = dpart[0][t] + dpart[1][t] + dpart[2][t] + dpart[3][t];
}

// ---------------- ctx merge: sum 8 k-slices, normalize, emit bf16 ctxT -----
__global__ __launch_bounds__(256)
void ctx_merge(const float* __restrict__ pctx, const float* __restrict__ pden,
               bf16* __restrict__ ctxT)
{
  int bh = blockIdx.x;
  int t = threadIdx.x, lane2 = t & 63, fg = t >> 6;
  __shared__ float rden[64];
  if (t < 64) {
    float s = 0.f;
    for (int kc = 0; kc < 8; ++kc) s += pden[(bh * 8 + kc) * 64 + t];
    rden[t] = 1.0f / s;
  }
  __syncthreads();
  int fr2 = lane2 & 15, g2 = lane2 >> 4;
#pragma unroll
  for (int ff = 0; ff < 4; ++ff) {
    int f = fg * 4 + ff;
    int mi = f >> 2, ni = f & 3;
    f32x4 s = {};
#pragma unroll
    for (int kc = 0; kc < 8; ++kc)
      s += *(const f32x4*)&pctx[(((size_t)(bh * 8 + kc)) * 16 + f) * 256 + lane2 * 4];
    int e = ni * 16 + fr2;
    int d0 = mi * 16 + g2 * 4;
    ushort4 pk;
    pk.x = f2bfu(s[0] * rden[d0 + 0]);
    pk.y = f2bfu(s[1] * rden[d0 + 1]);
    pk.z = f2bfu(s[2] * rden[d0 + 2]);
    pk.w = f2bfu(s[3] * rden[d0 + 3]);
    *(ushort4*)((unsigned short*)ctxT + ((size_t)bh * 64 + e) * 64 + d0) = pk;
  }
}

// ---------------- attn: softmax(q)*DH^-.5 @ ctx -> attn_hm, MFMA -----------
__global__ __launch_bounds__(256)
void attn_kernel(const bf16* __restrict__ qhm, const bf16* __restrict__ ctxT,
                 bf16* __restrict__ attn)
{
  int blk = blockIdx.x;           // bh*16 + chunk
  int chunk = blk & 15, bh = blk >> 4;
  int t = threadIdx.x, lane = t & 63, wid = t >> 6;
  __shared__ bf16 P[256 * 64];    // 32 KiB: [wave region][row][8 blk x 8]
  __shared__ bf16 CT[64 * 64];    // 8 KiB:  [e][8 blk x 8]

  // stage ctxT (swizzled)
  {
    const unsigned short* cg = (const unsigned short*)ctxT + (size_t)bh * 4096;
#pragma unroll
    for (int r = 0; r < 2; ++r) {
      int idx = r * 256 + t;                 // 16B-chunk index
      int e = idx >> 3, b = idx & 7;
      bf16x8 v = *(const bf16x8*)(cg + idx * 8);
      *(bf16x8*)&CT[e * 64 + ((b ^ (e & 7)) * 8)] = v;
    }
  }
  // q softmax, thread-per-row
  {
    int s = chunk * 256 + t;
    const unsigned short* qp = (const unsigned short*)qhm + ((size_t)bh * 4096 + s) * 64;
    float p[64];
#pragma unroll
    for (int j = 0; j < 8; ++j) {
      bf16x8 q8 = *(const bf16x8*)(qp + j * 8);
#pragma unroll
      for (int i = 0; i < 8; ++i) p[j * 8 + i] = bf2f(q8[i]);
    }
    float mx = p[0];
#pragma unroll
    for (int d = 1; d < 64; ++d) mx = fmaxf(mx, p[d]);
    float sum = 0.f;
#pragma unroll
    for (int d = 0; d < 64; ++d) { p[d] = __expf(p[d] - mx); sum += p[d]; }
    float f = 0.125f / sum;       // DH^-0.5
    bf16* pb = &P[(t >> 6) * 4096 + (t & 63) * 64];
#pragma unroll
    for (int b = 0; b < 8; ++b) {
      bf16x8 pk;
#pragma unroll
      for (int i = 0; i < 8; ++i) pk[i] = (short)f2bfu(p[b * 8 + i] * f);
      *(bf16x8*)&pb[((b ^ (t & 7)) * 8)] = pk;
    }
  }
  __syncthreads();

  // mfma: wave computes its 64 rows x 64 cols
  const int fr = lane & 15, g = lane >> 4;
  f32x4 acc[4][4] = {};
  const bf16* Pw = &P[wid * 4096];
#pragma unroll
  for (int ks = 0; ks < 2; ++ks) {
    bf16x8 av[4], bv[4];
#pragma unroll
    for (int mi = 0; mi < 4; ++mi) {
      int r = mi * 16 + fr;
      av[mi] = *(const bf16x8*)&Pw[r * 64 + (((ks * 4 + g) ^ (r & 7)) * 8)];
    }
#pragma unroll
    for (int ni = 0; ni < 4; ++ni) {
      int e = ni * 16 + fr;
      bv[ni] = *(const bf16x8*)&CT[e * 64 + (((ks * 4 + g) ^ (e & 7)) * 8)];
    }
#pragma unroll
    for (int mi = 0; mi < 4; ++mi)
#pragma unroll
      for (int ni = 0; ni < 4; ++ni)
        acc[mi][ni] = MFMA_(av[mi], bv[ni], acc[mi][ni], 0, 0, 0);
  }
  // store attn_hm[bh][s][e]
  unsigned short* ob = (unsigned short*)attn +
      ((size_t)bh * 4096 + chunk * 256 + wid * 64) * 64;
#pragma unroll
  for (int mi = 0; mi < 4; ++mi)
#pragma unroll
    for (int ni = 0; ni < 4; ++ni) {
      int e = ni * 16 + fr;
#pragma unroll
      for (int j = 0; j < 4; ++j) {
        int r = mi * 16 + g * 4 + j;
        ob[(size_t)r * 64 + e] = f2bfu(acc[mi][ni][j]);
      }
    }
}

// ---------------- ws layout (bytes) — total 160 MiB -------------------------
// weights [0,12M) | ctxT [12M,12.5M) | pctx [13.5M,21.5M) | pden [21.5M,..) |
// attn_hm [32M,64M) | q_hm [64M,96M) | kT [96M,128M) | vT [128M,160M)
// after attn: z over q_hm; x2b over kT; y over vT
#define OFF_WQKVT  ((size_t)0)
#define OFF_WOT    ((size_t)6291456)
#define OFF_W1T    ((size_t)8388608)
#define OFF_W2T    ((size_t)10485760)
#define OFF_CTXT   ((size_t)12582912)
#define OFF_PCTX   ((size_t)13631488)
#define OFF_PDEN   ((size_t)22020096)
#define OFF_ATTN   ((size_t)33554432)
#define OFF_H      OFF_ATTN
#define OFF_QHM    ((size_t)67108864)
#define OFF_KT     ((size_t)100663296)
#define OFF_VT     ((size_t)134217728)
#define OFF_Z      OFF_QHM
#define OFF_X2B    OFF_KT
#define OFF_Y      OFF_VT

extern "C" void kernel_launch(void* const* d_in, const int* in_sizes, int n_in,
                              void* d_out, int out_size, void* d_ws, size_t ws_size,
                              hipStream_t stream)
{
  const float* x     = (const float*)d_in[0];
  const float* ln1_g = (const float*)d_in[1];
  const float* ln1_b = (const float*)d_in[2];
  const float* Wqkv  = (const float*)d_in[3];
  const float* Wo    = (const float*)d_in[4];
  const float* bo    = (const float*)d_in[5];
  const float* ln2_g = (const float*)d_in[6];
  const float* ln2_b = (const float*)d_in[7];
  const float* W1    = (const float*)d_in[8];
  const float* b1    = (const float*)d_in[9];
  const float* W2    = (const float*)d_in[10];
  const float* b2    = (const float*)d_in[11];
  float* out = (float*)d_out;
  char* ws = (char*)d_ws;

  bf16*  h     = (bf16*)(ws + OFF_H);       // LN1 out (dead after qkv gemm)
  bf16*  attn  = (bf16*)(ws + OFF_ATTN);
  bf16*  qhm   = (bf16*)(ws + OFF_QHM);
  bf16*  kT    = (bf16*)(ws + OFF_KT);
  bf16*  vT    = (bf16*)(ws + OFF_VT);
  bf16*  ctxT  = (bf16*)(ws + OFF_CTXT);
  float* pctx  = (float*)(ws + OFF_PCTX);
  float* pden  = (float*)(ws + OFF_PDEN);
  bf16*  x2b   = (bf16*)(ws + OFF_X2B);
  bf16*  y     = (bf16*)(ws + OFF_Y);
  bf16*  z     = (bf16*)(ws + OFF_Z);
  bf16*  wqkvt = (bf16*)(ws + OFF_WQKVT);
  bf16*  wot   = (bf16*)(ws + OFF_WOT);
  bf16*  w1t   = (bf16*)(ws + OFF_W1T);
  bf16*  w2t   = (bf16*)(ws + OFF_W2T);

  const size_t GEMM_LDS = 131072;

  transpose_cast4<<<dim3(192, 32), 256, 0, stream>>>(Wqkv, Wo, W1, W2,
                                                     wqkvt, wot, w1t, w2t);

  ln_kernel<true, false><<<BS_, 256, 0, stream>>>(x, nullptr, ln1_g, ln1_b, h);

  // qkv gemm: scatter epilogue -> q_hm, kT, vT
  gemm256<EPI_QKV, false><<<(N3_ / 256) * (BS_ / 256), 512, GEMM_LDS, stream>>>(
      h, wqkvt, nullptr, qhm, nullptr, nullptr, nullptr, kT, vT, BS_, N3_, D_);

  // ctx (MFMA, split-K=8) -> ctxT bf16
  ctx_partial<<<512, 256, 0, stream>>>(kT, vT, pctx, pden);
  ctx_merge<<<64, 256, 0, stream>>>(pctx, pden, ctxT);

  // attn (MFMA) -> attn_hm
  attn_kernel<<<1024, 256, 0, stream>>>(qhm, ctxT, attn);

  // x2 = attn @ Wo + bo + x  (AHM staging from head-major attn)
  gemm256<EPI_BIAS_RES_BF16, true><<<(D_ / 256) * (BS_ / 256), 512, GEMM_LDS, stream>>>(
      attn, wot, nullptr, x2b, bo, x, nullptr, nullptr, nullptr, BS_, D_, D_);

  ln_kernel<false, true><<<BS_, 256, 0, stream>>>(nullptr, x2b, ln2_g, ln2_b, y);

  gemm256<EPI_BIAS_GELU_BF16, false><<<(D_ / 256) * (BS_ / 256), 512, GEMM_LDS, stream>>>(
      y, w1t, nullptr, z, b1, nullptr, nullptr, nullptr, nullptr, BS_, D_, D_);

  gemm256<EPI_BIAS_RESB_F32, false><<<(D_ / 256) * (BS_ / 256), 512, GEMM_LDS, stream>>>(
      z, w2t, out, nullptr, b2, nullptr, x2b, nullptr, nullptr, BS_, D_, D_);
}

// Round 10
// 350.745 us; speedup vs baseline: 1.4518x; 1.0081x over previous
//
#include <hip/hip_runtime.h>
#include <hip/hip_bf16.h>
#include <math.h>

#define B_   4
#define S_   4096
#define D_   1024
#define H_   16
#define DH_  64
#define BS_  (B_ * S_)     // 16384 rows
#define N3_  3072          // 3 * INNER

using bf16 = __hip_bfloat16;
typedef __attribute__((ext_vector_type(8))) short bf16x8;
typedef __attribute__((ext_vector_type(4))) float f32x4;

#define GAS __attribute__((address_space(1)))
#define LAS __attribute__((address_space(3)))

__device__ __forceinline__ void gload_lds16(const bf16* g, bf16* l) {
  __builtin_amdgcn_global_load_lds((const GAS void*)g, (LAS void*)l, 16, 0, 0);
}

__device__ __forceinline__ float bf2f(short u) {
  unsigned int x = ((unsigned int)(unsigned short)u) << 16;
  return __builtin_bit_cast(float, x);
}
__device__ __forceinline__ unsigned short f2bfu(float f) {
  bf16 t = __float2bfloat16(f);
  return *(unsigned short*)&t;
}

// ------------- fused prep: LN1(+PE) AND 4x weight transpose, one launch ----
// grid: [0,16384) = LN1 rows; [16384, 16384+6144) = transpose tiles.
__global__ __launch_bounds__(256)
void prep_kernel(const float* __restrict__ x, const float* __restrict__ ln1_g,
                 const float* __restrict__ ln1_b, bf16* __restrict__ h,
                 const float* __restrict__ Wqkv, const float* __restrict__ Wo,
                 const float* __restrict__ W1, const float* __restrict__ W2,
                 bf16* __restrict__ wqkvt, bf16* __restrict__ wot,
                 bf16* __restrict__ w1t, bf16* __restrict__ w2t)
{
  int bid = blockIdx.x;
  int t = threadIdx.x;
  if (bid < BS_) {
    // ---- LN1 + positional encoding ----
    int row = bid;
    float4 v = ((const float4*)(x + (size_t)row * D_))[t];
    float s  = v.x + v.y + v.z + v.w;
    float ss = v.x * v.x + v.y * v.y + v.z * v.z + v.w * v.w;
#pragma unroll
    for (int o = 32; o > 0; o >>= 1) { s += __shfl_xor(s, o); ss += __shfl_xor(ss, o); }
    __shared__ float red[8];
    int wid = t >> 6, lane = t & 63;
    if (lane == 0) { red[wid] = s; red[4 + wid] = ss; }
    __syncthreads();
    s  = red[0] + red[1] + red[2] + red[3];
    ss = red[4] + red[5] + red[6] + red[7];
    float mean = s * (1.0f / D_);
    float var  = ss * (1.0f / D_) - mean * mean;
    float rs   = rsqrtf(var + 1e-6f);
    int d0 = t * 4;
    const float4 g4 = ((const float4*)ln1_g)[t];
    const float4 b4 = ((const float4*)ln1_b)[t];
    float o0 = (v.x - mean) * rs * g4.x + b4.x;
    float o1 = (v.y - mean) * rs * g4.y + b4.y;
    float o2 = (v.z - mean) * rs * g4.z + b4.z;
    float o3 = (v.w - mean) * rs * g4.w + b4.w;
    const float C = -0.0089944730194f;   // -ln(10000)/1024
    float p = (float)(row & (S_ - 1));
    float sn, cs;
    __sincosf(p * __expf((float)d0 * C), &sn, &cs);        o0 += sn; o1 += cs;
    __sincosf(p * __expf((float)(d0 + 2) * C), &sn, &cs);  o2 += sn; o3 += cs;
    ushort4 pk;
    pk.x = f2bfu(o0); pk.y = f2bfu(o1); pk.z = f2bfu(o2); pk.w = f2bfu(o3);
    ((ushort4*)h)[(size_t)row * (D_ / 4) + t] = pk;
  } else {
    // ---- weight transpose: W[K=1024][N] f32 -> Wt[N][1024] bf16 ----
    int e = bid - BS_;
    int gx = e % 192, ky = e / 192;
    __shared__ float tile[32][33];
    const float* W; bf16* Wt; int N, xo;
    if (gx < 96)        { W = Wqkv; Wt = wqkvt; N = N3_; xo = gx; }
    else if (gx < 128)  { W = Wo;   Wt = wot;   N = D_;  xo = gx - 96; }
    else if (gx < 160)  { W = W1;   Wt = w1t;   N = D_;  xo = gx - 128; }
    else                { W = W2;   Wt = w2t;   N = D_;  xo = gx - 160; }
    int n0 = xo * 32, k0 = ky * 32;
    int tx = t & 31, ty = t >> 5;   // 32 x 8
#pragma unroll
    for (int j = 0; j < 32; j += 8)
      tile[ty + j][tx] = W[(size_t)(k0 + ty + j) * N + n0 + tx];
    __syncthreads();
#pragma unroll
    for (int j = 0; j < 32; j += 8)
      Wt[(size_t)(n0 + ty + j) * 1024 + k0 + tx] = __float2bfloat16(tile[tx][ty + j]);
  }
}

// ---------------- LayerNorm bf16-in -> bf16 (LN2) --------------------------
__global__ __launch_bounds__(256)
void ln_kernel(const bf16* __restrict__ Xb, const float* __restrict__ G,
               const float* __restrict__ Bv, bf16* __restrict__ out)
{
  int row = blockIdx.x;
  int t = threadIdx.x;
  ushort4 u = ((const ushort4*)Xb)[(size_t)row * (D_ / 4) + t];
  float4 v;
  v.x = bf2f(u.x); v.y = bf2f(u.y); v.z = bf2f(u.z); v.w = bf2f(u.w);
  float s  = v.x + v.y + v.z + v.w;
  float ss = v.x * v.x + v.y * v.y + v.z * v.z + v.w * v.w;
#pragma unroll
  for (int o = 32; o > 0; o >>= 1) { s += __shfl_xor(s, o); ss += __shfl_xor(ss, o); }
  __shared__ float red[8];
  int wid = t >> 6, lane = t & 63;
  if (lane == 0) { red[wid] = s; red[4 + wid] = ss; }
  __syncthreads();
  s  = red[0] + red[1] + red[2] + red[3];
  ss = red[4] + red[5] + red[6] + red[7];
  float mean = s * (1.0f / D_);
  float var  = ss * (1.0f / D_) - mean * mean;
  float rs   = rsqrtf(var + 1e-6f);
  const float4 g4 = ((const float4*)G)[t];
  const float4 b4 = ((const float4*)Bv)[t];
  ushort4 pk;
  pk.x = f2bfu((v.x - mean) * rs * g4.x + b4.x);
  pk.y = f2bfu((v.y - mean) * rs * g4.y + b4.y);
  pk.z = f2bfu((v.z - mean) * rs * g4.z + b4.z);
  pk.w = f2bfu((v.w - mean) * rs * g4.w + b4.w);
  ((ushort4*)out)[(size_t)row * (D_ / 4) + t] = pk;
}

// ---------------- 256x256 8-phase bf16 MFMA GEMM ---------------------------
// K-loop proven (r5-r9). New: LDS-repack coalesced epilogues (bf16 tile in
// LDS with 16B-unit XOR swizzle, vectorized readback w/ bias/res/gelu);
// phantom prefetch targets last tile (L2-hot) instead of tile 0.
enum { EPI_QKV = 0, EPI_BIAS_RES_BF16 = 1, EPI_BIAS_GELU_BF16 = 2, EPI_BIAS_RESB_F32 = 3 };

#define MFMA_ __builtin_amdgcn_mfma_f32_16x16x32_bf16

template<int EPI, bool AHM>
__global__ __launch_bounds__(512)
void gemm256(const bf16* __restrict__ A, const bf16* __restrict__ Bt,
             float* __restrict__ Cf, bf16* __restrict__ Cb,
             const float* __restrict__ bias, const float* __restrict__ resf,
             const bf16* __restrict__ resb,
             bf16* __restrict__ Ck, bf16* __restrict__ Cv,
             int M, int N, int K)
{
  extern __shared__ __align__(16) char smem[];
  bf16* lds = (bf16*)smem;

  const int t = threadIdx.x;
  const int wid = t >> 6, lane = t & 63;
  const int wr = wid >> 2, wc = wid & 3;        // 2 x 4 waves
  // XCD-aware 2D-chunked swizzle (nty==64, ntx%4==0, grid%8==0)
  const int bid = blockIdx.x;
  const int c = bid & 7;
  const int w = bid >> 3;
  const int sst = w >> 4;
  const int ii = w & 15;
  const int txg = sst >> 1, tyg = sst & 1;
  const int iy = ii & 3, ix = ii >> 2;
  const int ty = c * 8 + tyg * 4 + iy;
  const int tx = txg * 4 + ix;
  const int m0 = ty << 8, n0 = tx << 8;

  const bf16* Ab = AHM
      ? A + (((size_t)(m0 >> 12) * 16) * 4096 + (m0 & 4095)) * 64
      : A + (size_t)m0 * K;
  const bf16* Bb = Bt + (size_t)n0 * K;

  const int srow = t >> 2;
  const int scol = (((t & 3) ^ ((t >> 3) & 3)) * 8);
  const int NT = K >> 6;
  const int fr = lane & 15;
  const int fksw = (((lane >> 4) ^ ((lane >> 1) & 3)) * 8);

  f32x4 acc[8][4] = {};

  #define LDSHALF(b, mat, kh) (lds + (((((b) << 1) + (mat)) << 1) + (kh)) * 8192)

  // buffer index from bkt; source address from akt (phantom -> L2-hot last tile)
  #define STAGE(bkt, akt, mat, kh) do {                                        \
    bf16* _dst = LDSHALF((bkt) & 1, (mat), (kh)) + t * 8;                      \
    const int _ktk = (akt);                                                    \
    if ((mat) == 0 && AHM) {                                                   \
      const bf16* _sb = Ab + (size_t)_ktk * 262144 + (size_t)srow * 64         \
                        + (kh) * 32 + scol;                                    \
      gload_lds16(_sb, _dst);                                                  \
      gload_lds16(_sb + 8192, _dst + 4096);                                    \
    } else {                                                                   \
      const bf16* _sb = ((mat) == 0 ? Ab : Bb) + (size_t)srow * K              \
                        + (_ktk << 6) + (kh) * 32 + scol;                      \
      gload_lds16(_sb, _dst);                                                  \
      gload_lds16(_sb + (size_t)128 * K, _dst + 4096);                         \
    }                                                                          \
  } while (0)

  STAGE(0, 0, 0, 0); STAGE(0, 0, 1, 0);
  STAGE(0, 0, 0, 1); STAGE(0, 0, 1, 1);
  asm volatile("s_waitcnt vmcnt(4)" ::: "memory");
  __builtin_amdgcn_s_barrier();

#pragma unroll 2
  for (int kt = 0; kt < NT; ++kt) {
    const int cur = kt & 1;
    const int nk = (kt + 1 < NT) ? (kt + 1) : (NT - 1);   // phantom = last tile
    const bf16* hA0 = LDSHALF(cur, 0, 0);
    const bf16* hB0 = LDSHALF(cur, 1, 0);
    const bf16* hA1 = LDSHALF(cur, 0, 1);
    const bf16* hB1 = LDSHALF(cur, 1, 1);
    bf16x8 a[8], b0, b1, b2, b3;

    // ---- phase 1 ----
#pragma unroll
    for (int mi = 0; mi < 8; ++mi)
      a[mi] = *(const bf16x8*)&hA0[(wr * 128 + mi * 16 + fr) * 32 + fksw];
    b0 = *(const bf16x8*)&hB0[(wc * 64 +  0 + fr) * 32 + fksw];
    b1 = *(const bf16x8*)&hB0[(wc * 64 + 16 + fr) * 32 + fksw];
    STAGE(kt + 1, nk, 0, 0);
    __builtin_amdgcn_s_barrier();
    __builtin_amdgcn_s_setprio(1);
#pragma unroll
    for (int mi = 0; mi < 8; ++mi) {
      acc[mi][0] = MFMA_(a[mi], b0, acc[mi][0], 0, 0, 0);
      acc[mi][1] = MFMA_(a[mi], b1, acc[mi][1], 0, 0, 0);
    }
    __builtin_amdgcn_s_setprio(0);
    __builtin_amdgcn_s_barrier();

    // ---- phase 2 ----
    b2 = *(const bf16x8*)&hB0[(wc * 64 + 32 + fr) * 32 + fksw];
    b3 = *(const bf16x8*)&hB0[(wc * 64 + 48 + fr) * 32 + fksw];
    STAGE(kt + 1, nk, 1, 0);
    __builtin_amdgcn_s_barrier();
    __builtin_amdgcn_s_setprio(1);
#pragma unroll
    for (int mi = 0; mi < 8; ++mi) {
      acc[mi][2] = MFMA_(a[mi], b2, acc[mi][2], 0, 0, 0);
      acc[mi][3] = MFMA_(a[mi], b3, acc[mi][3], 0, 0, 0);
    }
    __builtin_amdgcn_s_setprio(0);
    asm volatile("s_waitcnt vmcnt(4)" ::: "memory");
    __builtin_amdgcn_s_barrier();

    // ---- phase 3 ----
#pragma unroll
    for (int mi = 0; mi < 8; ++mi)
      a[mi] = *(const bf16x8*)&hA1[(wr * 128 + mi * 16 + fr) * 32 + fksw];
    b0 = *(const bf16x8*)&hB1[(wc * 64 +  0 + fr) * 32 + fksw];
    b1 = *(const bf16x8*)&hB1[(wc * 64 + 16 + fr) * 32 + fksw];
    STAGE(kt + 1, nk, 0, 1);
    __builtin_amdgcn_s_barrier();
    __builtin_amdgcn_s_setprio(1);
#pragma unroll
    for (int mi = 0; mi < 8; ++mi) {
      acc[mi][0] = MFMA_(a[mi], b0, acc[mi][0], 0, 0, 0);
      acc[mi][1] = MFMA_(a[mi], b1, acc[mi][1], 0, 0, 0);
    }
    __builtin_amdgcn_s_setprio(0);
    __builtin_amdgcn_s_barrier();

    // ---- phase 4 ----
    b2 = *(const bf16x8*)&hB1[(wc * 64 + 32 + fr) * 32 + fksw];
    b3 = *(const bf16x8*)&hB1[(wc * 64 + 48 + fr) * 32 + fksw];
    STAGE(kt + 1, nk, 1, 1);
    __builtin_amdgcn_s_barrier();
    __builtin_amdgcn_s_setprio(1);
#pragma unroll
    for (int mi = 0; mi < 8; ++mi) {
      acc[mi][2] = MFMA_(a[mi], b2, acc[mi][2], 0, 0, 0);
      acc[mi][3] = MFMA_(a[mi], b3, acc[mi][3], 0, 0, 0);
    }
    __builtin_amdgcn_s_setprio(0);
    asm volatile("s_waitcnt vmcnt(4)" ::: "memory");
    __builtin_amdgcn_s_barrier();
  }
  asm volatile("s_waitcnt vmcnt(0)" ::: "memory");

  // ======== epilogue ========
  unsigned short* ot = (unsigned short*)lds;   // 256x256 bf16 tile, swizzled units

  const bool q_repack = (EPI == EPI_QKV) && (n0 < 1024);
  if (EPI != EPI_QKV || q_repack) {
    // dump acc -> LDS bf16, 16B-unit XOR swizzle (unit ^= row&7)
#pragma unroll
    for (int mi = 0; mi < 8; ++mi) {
#pragma unroll
      for (int ni = 0; ni < 4; ++ni) {
#pragma unroll
        for (int j = 0; j < 4; ++j) {
          int row = wr * 128 + mi * 16 + (lane >> 4) * 4 + j;
          int col = wc * 64 + ni * 16 + fr;
          int u = col >> 3;
          int st = (u & ~7) | ((u ^ row) & 7);
          ot[row * 256 + st * 8 + (col & 7)] = f2bfu(acc[mi][ni][j]);
        }
      }
    }
    __syncthreads();
  }

  if (EPI == EPI_QKV) {
    const int brow = m0 >> 12;           // batch (tiles never straddle b)
    const int mrow = m0 & 4095;          // s-base within batch
    if (q_repack) {
      // q: coalesced readback -> q_hm[bh][s][dd]
      int tq = t & 3, trow = t >> 2;     // 128 rows per pass
#pragma unroll
      for (int p = 0; p < 2; ++p) {
        int row = p * 128 + trow;
        int sglob = mrow + row;
#pragma unroll
        for (int i = 0; i < 8; ++i) {
          int uu = i * 4 + tq;           // logical unit 0..31
          int hl = uu >> 3, k = uu & 7;
          int st = (uu & ~7) | ((uu ^ row) & 7);
          bf16x8 v = *(const bf16x8*)&ot[row * 256 + st * 8];
          unsigned short* dst = (unsigned short*)Cb +
            (((size_t)(brow * 16 + (n0 >> 6) + hl) * 4096 + sglob) * 64 + k * 8);
          *(bf16x8*)dst = v;
        }
      }
    } else {
      // k/v: direct ushort4 along s (as r8/r9, passing)
      int qsel = n0 >> 10;
#pragma unroll
      for (int mi = 0; mi < 8; ++mi) {
        int sloc = mrow + wr * 128 + mi * 16 + (lane >> 4) * 4;
#pragma unroll
        for (int ni = 0; ni < 4; ++ni) {
          int col = n0 + wc * 64 + ni * 16 + fr;
          int hh = (col >> 6) & 15;
          int dd = col & 63;
          unsigned short* kp = (unsigned short*)(qsel == 1 ? Ck : Cv) +
            (((size_t)(brow * 16 + hh) * 64 + dd) * 4096 + sloc);
          ushort4 pk;
          pk.x = f2bfu(acc[mi][ni][0]); pk.y = f2bfu(acc[mi][ni][1]);
          pk.z = f2bfu(acc[mi][ni][2]); pk.w = f2bfu(acc[mi][ni][3]);
          *(ushort4*)kp = pk;
        }
      }
    }
  } else {
    // row-major epilogues: lane = 16B unit, 2 rows/wave-iter, 16 iters
    int rlane = lane & 31;
    int rrow0 = lane >> 5;
    float bias8[8];
    *(float4*)&bias8[0] = *(const float4*)&bias[n0 + rlane * 8];
    *(float4*)&bias8[4] = *(const float4*)&bias[n0 + rlane * 8 + 4];
#pragma unroll 4
    for (int it = 0; it < 16; ++it) {
      int row = wid * 32 + it * 2 + rrow0;
      int st = (rlane & ~7) | ((rlane ^ row) & 7);
      bf16x8 v8 = *(const bf16x8*)&ot[row * 256 + st * 8];
      int grow = m0 + row;
      float o[8];
#pragma unroll
      for (int q = 0; q < 8; ++q) o[q] = bf2f(v8[q]) + bias8[q];
      if (EPI == EPI_BIAS_RES_BF16) {
        const float* rp = resf + (size_t)grow * N + n0 + rlane * 8;
        float4 r0 = *(const float4*)rp, r1 = *(const float4*)(rp + 4);
        o[0] += r0.x; o[1] += r0.y; o[2] += r0.z; o[3] += r0.w;
        o[4] += r1.x; o[5] += r1.y; o[6] += r1.z; o[7] += r1.w;
        bf16x8 wv;
#pragma unroll
        for (int q = 0; q < 8; ++q) wv[q] = (short)f2bfu(o[q]);
        *(bf16x8*)((unsigned short*)Cb + (size_t)grow * N + n0 + rlane * 8) = wv;
      } else if (EPI == EPI_BIAS_GELU_BF16) {
        bf16x8 wv;
#pragma unroll
        for (int q = 0; q < 8; ++q) {
          float u = o[q];
          u = 0.5f * u * (1.0f + erff(u * 0.70710678118654752f));
          wv[q] = (short)f2bfu(u);
        }
        *(bf16x8*)((unsigned short*)Cb + (size_t)grow * N + n0 + rlane * 8) = wv;
      } else {   // EPI_BIAS_RESB_F32
        const unsigned short* rp = (const unsigned short*)resb + (size_t)grow * N + n0 + rlane * 8;
        bf16x8 r8 = *(const bf16x8*)rp;
#pragma unroll
        for (int q = 0; q < 8; ++q) o[q] += bf2f(r8[q]);
        float4 s0, s1;
        s0.x = o[0]; s0.y = o[1]; s0.z = o[2]; s0.w = o[3];
        s1.x = o[4]; s1.y = o[5]; s1.z = o[6]; s1.w = o[7];
        float* op = Cf + (size_t)grow * N + n0 + rlane * 8;
        *(float4*)op = s0;
        *(float4*)(op + 4) = s1;
      }
    }
  }
  #undef STAGE
  #undef LDSHALF
}

// ---------------- ctx split-K partial: MFMA, den fused in-loop -------------
__global__ __launch_bounds__(256)
void ctx_partial(const bf16* __restrict__ kT, const bf16* __restrict__ vT,
                 float* __restrict__ pctx, float* __restrict__ pden)
{
  int blk = blockIdx.x;          // bh*8 + kc
  int kc = blk & 7, bh = blk >> 3;
  int t = threadIdx.x, lane = t & 63, wid = t >> 6;
  const int fr = lane & 15, g = lane >> 4;
  __shared__ float part[4][4096];
  __shared__ float dpart[4][64];

  f32x4 acc[4][4] = {};
  float dsum[4] = {0.f, 0.f, 0.f, 0.f};
  const unsigned short* kb = (const unsigned short*)kT + (size_t)bh * 64 * 4096;
  const unsigned short* vb = (const unsigned short*)vT + (size_t)bh * 64 * 4096;
  const int kbase = kc * 512 + wid * 128;
#pragma unroll
  for (int i = 0; i < 4; ++i) {
    int kofs = kbase + i * 32 + g * 8;
    bf16x8 av[4], bv[4];
#pragma unroll
    for (int mi = 0; mi < 4; ++mi) {
      bf16x8 kr = *(const bf16x8*)(kb + (size_t)(mi * 16 + fr) * 4096 + kofs);
      bf16x8 ae;
      float es = 0.f;
#pragma unroll
      for (int j = 0; j < 8; ++j) {
        float e = __expf(bf2f(kr[j]));
        es += e;
        ae[j] = (short)f2bfu(e);
      }
      dsum[mi] += es;
      av[mi] = ae;
      bv[mi] = *(const bf16x8*)(vb + (size_t)(mi * 16 + fr) * 4096 + kofs);
    }
#pragma unroll
    for (int mi = 0; mi < 4; ++mi)
#pragma unroll
      for (int ni = 0; ni < 4; ++ni)
        acc[mi][ni] = MFMA_(av[mi], bv[ni], acc[mi][ni], 0, 0, 0);
  }
#pragma unroll
  for (int mi = 0; mi < 4; ++mi) {
    dsum[mi] += __shfl_xor(dsum[mi], 16);
    dsum[mi] += __shfl_xor(dsum[mi], 32);
  }
#pragma unroll
  for (int mi = 0; mi < 4; ++mi)
#pragma unroll
    for (int ni = 0; ni < 4; ++ni)
      *(f32x4*)&part[wid][(mi * 4 + ni) * 256 + lane * 4] = acc[mi][ni];
  if (g == 0) {
#pragma unroll
    for (int mi = 0; mi < 4; ++mi) dpart[wid][mi * 16 + fr] = dsum[mi];
  }
  __syncthreads();
  int lane2 = t & 63, fg = t >> 6;
#pragma unroll
  for (int ff = 0; ff < 4; ++ff) {
    int f = fg * 4 + ff;
    f32x4 s = {};
#pragma unroll
    for (int ww = 0; ww < 4; ++ww)
      s += *(const f32x4*)&part[ww][f * 256 + lane2 * 4];
    *(f32x4*)&pctx[((size_t)blk * 16 + f) * 256 + lane2 * 4] = s;
  }
  if (t < 64)
    pden[blk * 64 + t] = dpart[0][t] + dpart[1][t] + dpart[2][t] + dpart[3][t];
}

// ---------------- ctx merge: sum 8 k-slices, normalize, emit bf16 ctxT -----
__global__ __launch_bounds__(256)
void ctx_merge(const float* __restrict__ pctx, const float* __restrict__ pden,
               bf16* __restrict__ ctxT)
{
  int bh = blockIdx.x;
  int t = threadIdx.x, lane2 = t & 63, fg = t >> 6;
  __shared__ float rden[64];
  if (t < 64) {
    float s = 0.f;
    for (int kc = 0; kc < 8; ++kc) s += pden[(bh * 8 + kc) * 64 + t];
    rden[t] = 1.0f / s;
  }
  __syncthreads();
  int fr2 = lane2 & 15, g2 = lane2 >> 4;
#pragma unroll
  for (int ff = 0; ff < 4; ++ff) {
    int f = fg * 4 + ff;
    int mi = f >> 2, ni = f & 3;
    f32x4 s = {};
#pragma unroll
    for (int kc = 0; kc < 8; ++kc)
      s += *(const f32x4*)&pctx[(((size_t)(bh * 8 + kc)) * 16 + f) * 256 + lane2 * 4];
    int e = ni * 16 + fr2;
    int d0 = mi * 16 + g2 * 4;
    ushort4 pk;
    pk.x = f2bfu(s[0] * rden[d0 + 0]);
    pk.y = f2bfu(s[1] * rden[d0 + 1]);
    pk.z = f2bfu(s[2] * rden[d0 + 2]);
    pk.w = f2bfu(s[3] * rden[d0 + 3]);
    *(ushort4*)((unsigned short*)ctxT + ((size_t)bh * 64 + e) * 64 + d0) = pk;
  }
}

// ---------------- attn: softmax(q)*DH^-.5 @ ctx -> attn_hm, MFMA -----------
__global__ __launch_bounds__(256)
void attn_kernel(const bf16* __restrict__ qhm, const bf16* __restrict__ ctxT,
                 bf16* __restrict__ attn)
{
  int blk = blockIdx.x;           // bh*16 + chunk
  int chunk = blk & 15, bh = blk >> 4;
  int t = threadIdx.x, lane = t & 63, wid = t >> 6;
  __shared__ bf16 P[256 * 64];
  __shared__ bf16 CT[64 * 64];

  {
    const unsigned short* cg = (const unsigned short*)ctxT + (size_t)bh * 4096;
#pragma unroll
    for (int r = 0; r < 2; ++r) {
      int idx = r * 256 + t;
      int e = idx >> 3, b = idx & 7;
      bf16x8 v = *(const bf16x8*)(cg + idx * 8);
      *(bf16x8*)&CT[e * 64 + ((b ^ (e & 7)) * 8)] = v;
    }
  }
  {
    int s = chunk * 256 + t;
    const unsigned short* qp = (const unsigned short*)qhm + ((size_t)bh * 4096 + s) * 64;
    float p[64];
#pragma unroll
    for (int j = 0; j < 8; ++j) {
      bf16x8 q8 = *(const bf16x8*)(qp + j * 8);
#pragma unroll
      for (int i = 0; i < 8; ++i) p[j * 8 + i] = bf2f(q8[i]);
    }
    float mx = p[0];
#pragma unroll
    for (int d = 1; d < 64; ++d) mx = fmaxf(mx, p[d]);
    float sum = 0.f;
#pragma unroll
    for (int d = 0; d < 64; ++d) { p[d] = __expf(p[d] - mx); sum += p[d]; }
    float f = 0.125f / sum;       // DH^-0.5
    bf16* pb = &P[(t >> 6) * 4096 + (t & 63) * 64];
#pragma unroll
    for (int b = 0; b < 8; ++b) {
      bf16x8 pk;
#pragma unroll
      for (int i = 0; i < 8; ++i) pk[i] = (short)f2bfu(p[b * 8 + i] * f);
      *(bf16x8*)&pb[((b ^ (t & 7)) * 8)] = pk;
    }
  }
  __syncthreads();

  const int fr = lane & 15, g = lane >> 4;
  f32x4 acc[4][4] = {};
  const bf16* Pw = &P[wid * 4096];
#pragma unroll
  for (int ks = 0; ks < 2; ++ks) {
    bf16x8 av[4], bv[4];
#pragma unroll
    for (int mi = 0; mi < 4; ++mi) {
      int r = mi * 16 + fr;
      av[mi] = *(const bf16x8*)&Pw[r * 64 + (((ks * 4 + g) ^ (r & 7)) * 8)];
    }
#pragma unroll
    for (int ni = 0; ni < 4; ++ni) {
      int e = ni * 16 + fr;
      bv[ni] = *(const bf16x8*)&CT[e * 64 + (((ks * 4 + g) ^ (e & 7)) * 8)];
    }
#pragma unroll
    for (int mi = 0; mi < 4; ++mi)
#pragma unroll
      for (int ni = 0; ni < 4; ++ni)
        acc[mi][ni] = MFMA_(av[mi], bv[ni], acc[mi][ni], 0, 0, 0);
  }
  unsigned short* ob = (unsigned short*)attn +
      ((size_t)bh * 4096 + chunk * 256 + wid * 64) * 64;
#pragma unroll
  for (int mi = 0; mi < 4; ++mi)
#pragma unroll
    for (int ni = 0; ni < 4; ++ni) {
      int e = ni * 16 + fr;
#pragma unroll
      for (int j = 0; j < 4; ++j) {
        int r = mi * 16 + g * 4 + j;
        ob[(size_t)r * 64 + e] = f2bfu(acc[mi][ni][j]);
      }
    }
}

// ---------------- ws layout (bytes) — total 160 MiB -------------------------
#define OFF_WQKVT  ((size_t)0)
#define OFF_WOT    ((size_t)6291456)
#define OFF_W1T    ((size_t)8388608)
#define OFF_W2T    ((size_t)10485760)
#define OFF_CTXT   ((size_t)12582912)
#define OFF_PCTX   ((size_t)13631488)
#define OFF_PDEN   ((size_t)22020096)
#define OFF_ATTN   ((size_t)33554432)
#define OFF_H      OFF_ATTN
#define OFF_QHM    ((size_t)67108864)
#define OFF_KT     ((size_t)100663296)
#define OFF_VT     ((size_t)134217728)
#define OFF_Z      OFF_QHM
#define OFF_X2B    OFF_KT
#define OFF_Y      OFF_VT

extern "C" void kernel_launch(void* const* d_in, const int* in_sizes, int n_in,
                              void* d_out, int out_size, void* d_ws, size_t ws_size,
                              hipStream_t stream)
{
  const float* x     = (const float*)d_in[0];
  const float* ln1_g = (const float*)d_in[1];
  const float* ln1_b = (const float*)d_in[2];
  const float* Wqkv  = (const float*)d_in[3];
  const float* Wo    = (const float*)d_in[4];
  const float* bo    = (const float*)d_in[5];
  const float* ln2_g = (const float*)d_in[6];
  const float* ln2_b = (const float*)d_in[7];
  const float* W1    = (const float*)d_in[8];
  const float* b1    = (const float*)d_in[9];
  const float* W2    = (const float*)d_in[10];
  const float* b2    = (const float*)d_in[11];
  float* out = (float*)d_out;
  char* ws = (char*)d_ws;

  bf16*  h     = (bf16*)(ws + OFF_H);
  bf16*  attn  = (bf16*)(ws + OFF_ATTN);
  bf16*  qhm   = (bf16*)(ws + OFF_QHM);
  bf16*  kT    = (bf16*)(ws + OFF_KT);
  bf16*  vT    = (bf16*)(ws + OFF_VT);
  bf16*  ctxT  = (bf16*)(ws + OFF_CTXT);
  float* pctx  = (float*)(ws + OFF_PCTX);
  float* pden  = (float*)(ws + OFF_PDEN);
  bf16*  x2b   = (bf16*)(ws + OFF_X2B);
  bf16*  y     = (bf16*)(ws + OFF_Y);
  bf16*  z     = (bf16*)(ws + OFF_Z);
  bf16*  wqkvt = (bf16*)(ws + OFF_WQKVT);
  bf16*  wot   = (bf16*)(ws + OFF_WOT);
  bf16*  w1t   = (bf16*)(ws + OFF_W1T);
  bf16*  w2t   = (bf16*)(ws + OFF_W2T);

  const size_t GEMM_LDS = 131072;

  // LN1(+PE) and weight transposes, one launch
  prep_kernel<<<BS_ + 192 * 32, 256, 0, stream>>>(
      x, ln1_g, ln1_b, h, Wqkv, Wo, W1, W2, wqkvt, wot, w1t, w2t);

  // qkv gemm: scatter epilogue -> q_hm, kT, vT
  gemm256<EPI_QKV, false><<<(N3_ / 256) * (BS_ / 256), 512, GEMM_LDS, stream>>>(
      h, wqkvt, nullptr, qhm, nullptr, nullptr, nullptr, kT, vT, BS_, N3_, D_);

  // ctx (MFMA, split-K=8) -> ctxT bf16
  ctx_partial<<<512, 256, 0, stream>>>(kT, vT, pctx, pden);
  ctx_merge<<<64, 256, 0, stream>>>(pctx, pden, ctxT);

  // attn (MFMA) -> attn_hm
  attn_kernel<<<1024, 256, 0, stream>>>(qhm, ctxT, attn);

  // x2 = attn @ Wo + bo + x  (AHM staging from head-major attn)
  gemm256<EPI_BIAS_RES_BF16, true><<<(D_ / 256) * (BS_ / 256), 512, GEMM_LDS, stream>>>(
      attn, wot, nullptr, x2b, bo, x, nullptr, nullptr, nullptr, BS_, D_, D_);

  ln_kernel<<<BS_, 256, 0, stream>>>(x2b, ln2_g, ln2_b, y);

  gemm256<EPI_BIAS_GELU_BF16, false><<<(D_ / 256) * (BS_ / 256), 512, GEMM_LDS, stream>>>(
      y, w1t, nullptr, z, b1, nullptr, nullptr, nullptr, nullptr, BS_, D_, D_);

  gemm256<EPI_BIAS_RESB_F32, false><<<(D_ / 256) * (BS_ / 256), 512, GEMM_LDS, stream>>>(
      z, w2t, out, nullptr, b2, nullptr, x2b, nullptr, nullptr, BS_, D_, D_);
}